// Round 9
// baseline (984.606 us; speedup 1.0000x reference)
//
#include <hip/hip_runtime.h>
#include <hip/hip_bf16.h>
#include <hip/hip_fp16.h>

constexpr int Nn = 100000;
constexpr int Ee = 1200000;
constexpr int Ll = 5;
constexpr int Gg = 128;
constexpr int PDim = 320; // L*D

typedef short short8 __attribute__((ext_vector_type(8)));
typedef float f32x4 __attribute__((ext_vector_type(4)));

union U4S8 { uint4 u; short8 s; };

__device__ inline ushort f2bf(float f) {
    const uint u = __float_as_uint(f);
    return (ushort)((u + 0x7fffu + ((u >> 16) & 1u)) >> 16);
}
__device__ inline uint pack2(float lo, float hi) {
    return (uint)f2bf(lo) | ((uint)f2bf(hi) << 16);
}
__device__ inline ushort f2h(float f) {
    const __half h = __float2half(f);
    return *(const ushort*)&h;
}
__device__ inline float h2f_lo(uint u) {
    const ushort s = (ushort)(u & 0xffffu);
    return __half2float(*(const __half*)&s);
}
__device__ inline float h2f_hi(uint u) {
    const ushort s = (ushort)(u >> 16);
    return __half2float(*(const __half*)&s);
}
// split x0,x1 into packed bf16 hi word + bf16 lo (residual) word
__device__ inline void split2(float x0, float x1, uint& hi, uint& lo) {
    const ushort h0 = f2bf(x0), h1 = f2bf(x1);
    hi = (uint)h0 | ((uint)h1 << 16);
    const float r0 = x0 - __uint_as_float((uint)h0 << 16);
    const float r1 = x1 - __uint_as_float((uint)h1 << 16);
    lo = pack2(r0, r1);
}

__device__ inline int lower_bound_i(const int* __restrict__ a, int n, int v)
{
    int lo = 0, hi = n;
    while (lo < hi) {
        const int m = (lo + hi) >> 1;
        if (a[m] < v) lo = m + 1; else hi = m;
    }
    return lo;
}

// ---------------------------------------------------------------------------
__global__ void init_cnt(const int* __restrict__ batch, int* __restrict__ cnt)
{
    const int t = threadIdx.x;
    if (t < Gg) {
        const int lo = lower_bound_i(batch, Nn, t);
        const int hi = lower_bound_i(batch, Nn, t + 1);
        cnt[t] = hi - lo;
    }
}

// ---------------------------------------------------------------------------
// Weight conversion: Ws + 5x W2 -> bf16 TRANSPOSED hi/lo ([col][k]).
// ---------------------------------------------------------------------------
__global__ __launch_bounds__(256) void conv_weights(
    const float* __restrict__ Ws, const float* __restrict__ W2,
    ushort* __restrict__ WThi, ushort* __restrict__ WTlo)
{
    const int m = blockIdx.x;
    const float* src = (m == 0) ? Ws : W2 + (size_t)(m - 1) * 4096;
    ushort* dh = WThi + (size_t)m * 4096;
    ushort* dl = WTlo + (size_t)m * 4096;
    const int t = threadIdx.x;
    const int col = t & 63;
    const int k0 = (t >> 6) * 16;
    #pragma unroll
    for (int i = 0; i < 16; i++) {
        const int k = k0 + i;
        const float w = src[k * 64 + col];
        const ushort h = f2bf(w);
        dh[col * 64 + k] = h;
        dl[col * 64 + k] = f2bf(w - __uint_as_float((uint)h << 16));
    }
}

// ---------------------------------------------------------------------------
// Per-layer prep (grid 17). BN of previous layer derived from its stats,
// locally per block (no separate bn_finalize kernel).
//  blocks 0..15 : WT1' = split(scale[k] * W1[k][c]) (transposed hi/lo)
//  block  16    : shiftW1[c] = sum_k shift[k]*W1[k][c]; write sc5[l-1] (l>0)
// ---------------------------------------------------------------------------
__global__ __launch_bounds__(256) void prep_layer(
    const float* __restrict__ W1l, const float* __restrict__ statsPrev,
    const float* __restrict__ gammaPrev, const float* __restrict__ betaPrev,
    ushort* __restrict__ WT1hi, ushort* __restrict__ WT1lo,
    float* __restrict__ shiftW1, float* __restrict__ sc5Prev, int layer)
{
    const int b = blockIdx.x, t = threadIdx.x;
    if (b < 16) {
        const int idx = b * 256 + t;      // == c*64 + k
        const int c = idx >> 6, k = idx & 63;
        float scale = 1.f;
        if (layer > 0) {
            const float mean = statsPrev[k] * (1.f / Nn);
            const float var = statsPrev[64 + k] * (1.f / Nn) - mean * mean;
            scale = gammaPrev[k] * rsqrtf(var + 1e-5f);
        }
        const float wv = scale * W1l[k * 64 + c];
        const ushort h = f2bf(wv);
        WT1hi[idx] = h;
        WT1lo[idx] = f2bf(wv - __uint_as_float((uint)h << 16));
    } else {
        if (t < 64) {
            float s = 0.f;
            if (layer > 0) {
                for (int k = 0; k < 64; k++) {
                    const float mean = statsPrev[k] * (1.f / Nn);
                    const float var = statsPrev[64 + k] * (1.f / Nn) - mean * mean;
                    const float scale = gammaPrev[k] * rsqrtf(var + 1e-5f);
                    const float shift = betaPrev[k] - mean * scale;
                    s += shift * W1l[k * 64 + t];
                }
            }
            shiftW1[t] = s;
        }
        if (layer > 0 && t < 128) {
            const int k = t & 63;
            const float mean = statsPrev[k] * (1.f / Nn);
            const float var = statsPrev[64 + k] * (1.f / Nn) - mean * mean;
            const float scale = gammaPrev[k] * rsqrtf(var + 1e-5f);
            sc5Prev[t] = (t < 64) ? scale : (betaPrev[k] - mean * scale);
        }
    }
}

// ---------------------------------------------------------------------------
// Split-bf16 MFMA GEMM. A f32 rows (+A2 f32 if ADD2); W via WT hi/lo.
// acc += Alo*Whi + Ahi*Wlo + Ahi*Whi (f32-grade).
// SHIFT: epilogue adds (1+deg[row])*shiftW1[col], deg from rowptr diff.
// STATS: per-column sum/sumsq into stats. SHADOW: fp16 copy of Y.
// POOL: per-graph column sums into poolRaw (LDS accum, batch sorted).
// ---------------------------------------------------------------------------
template<bool ADD2, bool RELU, bool STATS, bool SHADOW, bool SHIFT, bool POOL>
__global__ __launch_bounds__(256) void gemm_mfma(
    const float* __restrict__ A1, const float* __restrict__ A2,
    const int* __restrict__ rowptr, const float* __restrict__ shiftW1,
    const ushort* __restrict__ WThi, const ushort* __restrict__ WTlo,
    const float* __restrict__ bias, float* __restrict__ Y,
    ushort* __restrict__ Ys, float* __restrict__ stats,
    const int* __restrict__ batch, float* __restrict__ poolRaw)
{
    const int t = threadIdx.x;
    const int w = t >> 6;
    const int l = t & 63;
    const int lr = l & 15;   // A-row / B-col within tile
    const int lk = l >> 4;   // k-group (8 elems each)
    const int blk = (int)blockIdx.x;

    __shared__ float red[2][4][4][16];   // STATS
    __shared__ float poolAcc[8][64];     // POOL

    if constexpr (POOL) {
        ((float*)poolAcc)[t] = 0.f;
        ((float*)poolAcc)[t + 256] = 0.f;
        __syncthreads();
    }

    // A fragments (NO early return: MFMA is wave-collective)
    const int arow = blk * 64 + w * 16 + lr;
    short8 aHi[2], aLo[2];
    if (arow < Nn) {
        float v0[8], v1[8];
        {
            const float* p = A1 + (size_t)arow * 64 + lk * 8;
            const float4 a = *(const float4*)p;
            const float4 b = *(const float4*)(p + 4);
            const float4 c = *(const float4*)(p + 32);
            const float4 d = *(const float4*)(p + 36);
            v0[0] = a.x; v0[1] = a.y; v0[2] = a.z; v0[3] = a.w;
            v0[4] = b.x; v0[5] = b.y; v0[6] = b.z; v0[7] = b.w;
            v1[0] = c.x; v1[1] = c.y; v1[2] = c.z; v1[3] = c.w;
            v1[4] = d.x; v1[5] = d.y; v1[6] = d.z; v1[7] = d.w;
        }
        if constexpr (ADD2) {
            const float* p = A2 + (size_t)arow * 64 + lk * 8;
            const float4 a = *(const float4*)p;
            const float4 b = *(const float4*)(p + 4);
            const float4 c = *(const float4*)(p + 32);
            const float4 d = *(const float4*)(p + 36);
            v0[0] += a.x; v0[1] += a.y; v0[2] += a.z; v0[3] += a.w;
            v0[4] += b.x; v0[5] += b.y; v0[6] += b.z; v0[7] += b.w;
            v1[0] += c.x; v1[1] += c.y; v1[2] += c.z; v1[3] += c.w;
            v1[4] += d.x; v1[5] += d.y; v1[6] += d.z; v1[7] += d.w;
        }
        U4S8 rh0, rl0, rh1, rl1;
        uint* ph0 = (uint*)&rh0.u; uint* pl0 = (uint*)&rl0.u;
        uint* ph1 = (uint*)&rh1.u; uint* pl1 = (uint*)&rl1.u;
        #pragma unroll
        for (int i = 0; i < 4; i++) {
            split2(v0[2 * i], v0[2 * i + 1], ph0[i], pl0[i]);
            split2(v1[2 * i], v1[2 * i + 1], ph1[i], pl1[i]);
        }
        aHi[0] = rh0.s; aLo[0] = rl0.s;
        aHi[1] = rh1.s; aLo[1] = rl1.s;
    } else {
        U4S8 z; z.u = make_uint4(0, 0, 0, 0);
        aHi[0] = aHi[1] = z.s;
        aLo[0] = aLo[1] = z.s;
    }

    // B fragments: col = nt*16+lr, k = c*32 + lk*8 (contiguous in WT)
    short8 bHi[4][2], bLo[4][2];
    #pragma unroll
    for (int nt = 0; nt < 4; nt++)
        #pragma unroll
        for (int c = 0; c < 2; c++) {
            const int off = (nt * 16 + lr) * 64 + c * 32 + lk * 8;
            U4S8 uh, ul;
            uh.u = *(const uint4*)(WThi + off);
            ul.u = *(const uint4*)(WTlo + off);
            bHi[nt][c] = uh.s;
            bLo[nt][c] = ul.s;
        }

    f32x4 acc[4] = {};
    #pragma unroll
    for (int nt = 0; nt < 4; nt++)
        #pragma unroll
        for (int c = 0; c < 2; c++) {
            acc[nt] = __builtin_amdgcn_mfma_f32_16x16x32_bf16(
                aLo[c], bHi[nt][c], acc[nt], 0, 0, 0);
            acc[nt] = __builtin_amdgcn_mfma_f32_16x16x32_bf16(
                aHi[c], bLo[nt][c], acc[nt], 0, 0, 0);
            acc[nt] = __builtin_amdgcn_mfma_f32_16x16x32_bf16(
                aHi[c], bHi[nt][c], acc[nt], 0, 0, 0);
        }

    // per-C-row info
    const int crow0 = blk * 64 + w * 16 + lk * 4;
    float dgf[4] = {};
    if constexpr (SHIFT) {
        if (crow0 < Nn) { // crow0 % 4 == 0, so crow0+4 <= Nn when crow0 < Nn
            const int4 rp = *(const int4*)(rowptr + crow0);
            const int rp4 = rowptr[crow0 + 4];
            dgf[0] = 1.f + (float)(rp.y - rp.x);
            dgf[1] = 1.f + (float)(rp.z - rp.y);
            dgf[2] = 1.f + (float)(rp.w - rp.z);
            dgf[3] = 1.f + (float)(rp4 - rp.w);
        }
    }
    int gidx[4] = {}; int gmin = 0, gmax = 0;
    if constexpr (POOL) {
        const int last = (blk * 64 + 63 < Nn - 1) ? blk * 64 + 63 : Nn - 1;
        gmin = batch[blk * 64];
        gmax = batch[last];
        if (crow0 < Nn) {
            const int4 bq = *(const int4*)(batch + crow0);
            gidx[0] = bq.x; gidx[1] = bq.y; gidx[2] = bq.z; gidx[3] = bq.w;
        }
    }

    // Epilogue: C/D layout col=lane&15, row=(lane>>4)*4+reg  [m89]
    float s[4], s2[4];
    #pragma unroll
    for (int nt = 0; nt < 4; nt++) {
        const int ccol = nt * 16 + lr;
        const float bb = bias[ccol];
        float sw = 0.f;
        if constexpr (SHIFT) sw = shiftW1[ccol];
        s[nt] = 0.f; s2[nt] = 0.f;
        #pragma unroll
        for (int j = 0; j < 4; j++) {
            const int crow = crow0 + j;
            if (crow < Nn) {
                float v = acc[nt][j] + bb;
                if constexpr (SHIFT) v = fmaf(dgf[j], sw, v);
                if constexpr (RELU) v = fmaxf(v, 0.f);
                Y[(size_t)crow * 64 + ccol] = v;
                if constexpr (SHADOW) Ys[(size_t)crow * 64 + ccol] = f2h(v);
                if constexpr (STATS) { s[nt] += v; s2[nt] += v * v; }
                if constexpr (POOL) {
                    const int gl = gidx[j] - gmin;
                    if (gl < 8) atomicAdd(&poolAcc[gl][ccol], v);
                    else atomicAdd(&poolRaw[(size_t)gidx[j] * 64 + ccol], v);
                }
            }
        }
    }

    if constexpr (POOL) {
        __syncthreads();
        if (t < 64) {
            for (int gl = 0; gl < 8; gl++) {
                if (gl > gmax - gmin) break;
                atomicAdd(&poolRaw[(size_t)(gmin + gl) * 64 + t], poolAcc[gl][t]);
            }
        }
    }

    if constexpr (STATS) {
        #pragma unroll
        for (int nt = 0; nt < 4; nt++) {
            s[nt]  += __shfl_xor(s[nt], 16);  s[nt]  += __shfl_xor(s[nt], 32);
            s2[nt] += __shfl_xor(s2[nt], 16); s2[nt] += __shfl_xor(s2[nt], 32);
        }
        if (l < 16) {
            #pragma unroll
            for (int nt = 0; nt < 4; nt++) {
                red[0][w][nt][l] = s[nt];
                red[1][w][nt][l] = s2[nt];
            }
        }
        __syncthreads();
        if (t < 64) { // column = (t>>4)*16 + (t&15) = t
            float ts = 0.f, ts2 = 0.f;
            #pragma unroll
            for (int wv = 0; wv < 4; wv++) {
                ts  += red[0][wv][t >> 4][t & 15];
                ts2 += red[1][wv][t >> 4][t & 15];
            }
            atomicAdd(&stats[t], ts);
            atomicAdd(&stats[64 + t], ts2);
        }
    }
}

// ---------------------------------------------------------------------------
// CSR build: degree count -> device-wide scan (3 phases) -> scatter-fill
// ---------------------------------------------------------------------------
__global__ __launch_bounds__(256) void count_deg(
    const int* __restrict__ ei, int* __restrict__ deg)
{
    const int e = blockIdx.x * 256 + threadIdx.x;
    if (e < Ee) atomicAdd(&deg[ei[Ee + e]], 1); // dst
}

constexpr int SCAN_TILE = 1024;
constexpr int SCAN_NBLK = (Nn + SCAN_TILE - 1) / SCAN_TILE; // 98

__global__ __launch_bounds__(256) void deg_block_reduce(
    const int* __restrict__ deg, int* __restrict__ blockSums)
{
    const int t = threadIdx.x;
    const int base = blockIdx.x * SCAN_TILE + t * 4;
    int s = 0;
    if (base + 4 <= Nn) {
        const int4 v = *(const int4*)(deg + base);
        s = v.x + v.y + v.z + v.w;
    } else {
        for (int i = 0; i < 4; i++) if (base + i < Nn) s += deg[base + i];
    }
    __shared__ int sh[256];
    sh[t] = s;
    __syncthreads();
    for (int off = 128; off > 0; off >>= 1) {
        if (t < off) sh[t] += sh[t + off];
        __syncthreads();
    }
    if (t == 0) blockSums[blockIdx.x] = sh[0];
}

__global__ __launch_bounds__(128) void scan_blocksums(int* __restrict__ blockSums)
{
    __shared__ int sh[128];
    const int t = threadIdx.x;
    const int v = (t < SCAN_NBLK) ? blockSums[t] : 0;
    sh[t] = v;
    __syncthreads();
    for (int off = 1; off < 128; off <<= 1) {
        const int u = (t >= off) ? sh[t - off] : 0;
        __syncthreads();
        sh[t] += u;
        __syncthreads();
    }
    if (t < SCAN_NBLK) blockSums[t] = sh[t] - v; // exclusive
}

__global__ __launch_bounds__(256) void deg_scan_scatter(
    const int* __restrict__ deg, const int* __restrict__ blockSums,
    int* __restrict__ rowptr, int* __restrict__ cursor)
{
    const int t = threadIdx.x;
    const int base = blockIdx.x * SCAN_TILE + t * 4;
    int v[4];
    int s = 0;
    #pragma unroll
    for (int i = 0; i < 4; i++) {
        const int idx = base + i;
        v[i] = (idx < Nn) ? deg[idx] : 0;
        s += v[i];
    }
    __shared__ int sh[256];
    sh[t] = s;
    __syncthreads();
    for (int off = 1; off < 256; off <<= 1) {
        const int u = (t >= off) ? sh[t - off] : 0;
        __syncthreads();
        sh[t] += u;
        __syncthreads();
    }
    int excl = sh[t] - s + blockSums[blockIdx.x];
    #pragma unroll
    for (int i = 0; i < 4; i++) {
        const int idx = base + i;
        if (idx < Nn) {
            rowptr[idx] = excl;
            cursor[idx] = excl;
            excl += v[i];
        }
    }
    if (blockIdx.x == 0 && t == 0) rowptr[Nn] = Ee;
}

__global__ __launch_bounds__(256) void scatter_fill(
    const int* __restrict__ ei, int* __restrict__ cursor, int* __restrict__ col)
{
    const int e = blockIdx.x * 256 + threadIdx.x;
    if (e >= Ee) return;
    const int s = ei[e];
    const int d = ei[Ee + e];
    const int pos = atomicAdd(&cursor[d], 1);
    col[pos] = s;
}

// ---------------------------------------------------------------------------
// Pull aggregation: agg[r] (f32) = sum_{j in row r} hs[col[j]] (fp16 shadow).
// 8 lanes per row (uint4 = 8 fp16 each), 32 rows per block. Grid exact.
// ---------------------------------------------------------------------------
__global__ __launch_bounds__(256) void gather_agg_h(
    const int* __restrict__ rowptr, const int* __restrict__ col,
    const ushort* __restrict__ hs, float* __restrict__ agg)
{
    const int r = blockIdx.x * 32 + (threadIdx.x >> 3);
    const int q = threadIdx.x & 7;
    const int beg = rowptr[r], end = rowptr[r + 1];
    float a[8] = {};
    for (int j = beg; j < end; j++) {
        const int s = col[j];
        const uint4 v = *(const uint4*)(hs + (size_t)s * 64 + q * 8);
        a[0] += h2f_lo(v.x); a[1] += h2f_hi(v.x);
        a[2] += h2f_lo(v.y); a[3] += h2f_hi(v.y);
        a[4] += h2f_lo(v.z); a[5] += h2f_hi(v.z);
        a[6] += h2f_lo(v.w); a[7] += h2f_hi(v.w);
    }
    float* o = agg + (size_t)r * 64 + q * 8;
    *(float4*)o       = make_float4(a[0], a[1], a[2], a[3]);
    *(float4*)(o + 4) = make_float4(a[4], a[5], a[6], a[7]);
}

// ---------------------------------------------------------------------------
// Final pooled transform: pooled[g][l*64+c] = sc_l[c]*poolRaw + cnt[g]*shift_l[c]
// ---------------------------------------------------------------------------
__global__ __launch_bounds__(256) void final_pool(
    const float* __restrict__ sc5, const float* __restrict__ stats4,
    const float* __restrict__ gamma, const float* __restrict__ beta,
    const float* __restrict__ poolRaw, const int* __restrict__ cnt,
    float* __restrict__ pooled)
{
    const int idx = blockIdx.x * 256 + threadIdx.x; // 40960
    const int c = idx & 63;
    const int g = (idx >> 6) & 127;
    const int l = idx >> 13;
    float scale, shift;
    if (l < 4) {
        scale = sc5[l * 128 + c];
        shift = sc5[l * 128 + 64 + c];
    } else {
        const float mean = stats4[c] * (1.f / Nn);
        const float var = stats4[64 + c] * (1.f / Nn) - mean * mean;
        scale = gamma[4 * 64 + c] * rsqrtf(var + 1e-5f);
        shift = beta[4 * 64 + c] - mean * scale;
    }
    pooled[g * PDim + l * 64 + c] =
        scale * poolRaw[(size_t)l * Gg * 64 + g * 64 + c] + (float)cnt[g] * shift;
}

// ---------------------------------------------------------------------------
// Proj head GEMM: (128,320)@(320,320)+b (f32, small).
// ---------------------------------------------------------------------------
template<bool RELU>
__global__ __launch_bounds__(256) void proj(
    const float* __restrict__ X, const float* __restrict__ W,
    const float* __restrict__ bias, float* __restrict__ Y)
{
    const int idx = blockIdx.x * 256 + threadIdx.x; // 40960 exact
    const int r = idx / PDim;
    const int c = idx - r * PDim;
    float acc = bias[c];
    #pragma unroll 8
    for (int k = 0; k < PDim; k++)
        acc = fmaf(X[r * PDim + k], W[k * PDim + c], acc);
    if constexpr (RELU) acc = fmaxf(acc, 0.f);
    Y[idx] = acc;
}

// ---------------------------------------------------------------------------
// Row-wise l2 normalize.
// ---------------------------------------------------------------------------
__global__ __launch_bounds__(64) void l2norm_rows(
    const float* __restrict__ X, float* __restrict__ out)
{
    const int r = blockIdx.x;
    const int l = threadIdx.x;
    float v[5];
    float s = 0.f;
    #pragma unroll
    for (int i = 0; i < 5; i++) {
        v[i] = X[r * PDim + i * 64 + l];
        s += v[i] * v[i];
    }
    #pragma unroll
    for (int off = 32; off > 0; off >>= 1) s += __shfl_down(s, off);
    s = __shfl(s, 0);
    const float d = fmaxf(sqrtf(s), 1e-12f);
    #pragma unroll
    for (int i = 0; i < 5; i++)
        out[r * PDim + i * 64 + l] = v[i] / d;
}

// ---------------------------------------------------------------------------
extern "C" void kernel_launch(void* const* d_in, const int* in_sizes, int n_in,
                              void* d_out, int out_size, void* d_ws, size_t ws_size,
                              hipStream_t stream)
{
    const float* x     = (const float*)d_in[0];
    const int*   ei    = (const int*)d_in[1];
    const int*   batch = (const int*)d_in[2];
    const float* Ws    = (const float*)d_in[3];
    const float* bs    = (const float*)d_in[4];
    const float* W1    = (const float*)d_in[5];
    const float* b1    = (const float*)d_in[6];
    const float* W2    = (const float*)d_in[7];
    const float* b2    = (const float*)d_in[8];
    const float* gamma = (const float*)d_in[9];
    const float* beta  = (const float*)d_in[10];
    const float* Wp1   = (const float*)d_in[11];
    const float* bp1   = (const float*)d_in[12];
    const float* Wp2   = (const float*)d_in[13];
    const float* bp2   = (const float*)d_in[14];
    float* out = (float*)d_out;

    // --- workspace layout ---
    // zero region first: stats[5*128] | poolRaw[5*G*64] | deg[Nn]
    float* stats   = (float*)d_ws;                       // 640
    float* poolRaw = stats + 5 * 128;                    // 40960
    int*   deg     = (int*)(poolRaw + 5 * Gg * 64);      // Nn
    int*   rowptr  = deg + Nn;                           // Nn+1
    int*   cursor  = rowptr + Nn + 1;                    // Nn
    int*   colidx  = cursor + Nn;                        // Ee
    int*   bsums   = colidx + Ee;                        // 98
    int*   cnt     = bsums + 128;                        // Gg
    float* sc5     = (float*)(cnt + Gg);                 // 5*128 (only 0..3 used)
    float* shiftW1 = sc5 + 5 * 128;                      // 64
    float* pooled  = shiftW1 + 64;                       // G*320
    float* ytmp    = pooled + Gg * PDim;                 // G*320
    float* ypro    = ytmp + Gg * PDim;                   // G*320
    // align to 16B for vector arrays
    size_t off = (size_t)((ypro + Gg * PDim) - (float*)d_ws);
    off = (off + 3) & ~(size_t)3;
    float*  Zf = (float*)d_ws + off;                     // N*64 f32
    float*  Mf = Zf + (size_t)Nn * 64;                   // N*64 f32
    float*  Gf = Mf + (size_t)Nn * 64;                   // N*64 f32
    ushort* Zs = (ushort*)(Gf + (size_t)Nn * 64);        // N*64 fp16
    ushort* WThi = Zs + (size_t)Nn * 64;                 // 6*4096
    ushort* WTlo = WThi + 6 * 4096;                      // 6*4096
    ushort* WT1hi = WTlo + 6 * 4096;                     // 4096
    ushort* WT1lo = WT1hi + 4096;                        // 4096

    const int gemmGrid = (Nn + 63) / 64;          // 1563
    const int edgeGrid = (Ee + 255) / 256;

    hipMemsetAsync(stats, 0, (5 * 128 + 5 * Gg * 64 + Nn) * sizeof(float), stream);
    init_cnt<<<1, 128, 0, stream>>>(batch, cnt);
    conv_weights<<<6, 256, 0, stream>>>(Ws, W2, WThi, WTlo);

    // CSR build
    count_deg<<<edgeGrid, 256, 0, stream>>>(ei, deg);
    deg_block_reduce<<<SCAN_NBLK, 256, 0, stream>>>(deg, bsums);
    scan_blocksums<<<1, 128, 0, stream>>>(bsums);
    deg_scan_scatter<<<SCAN_NBLK, 256, 0, stream>>>(deg, bsums, rowptr, cursor);
    scatter_fill<<<edgeGrid, 256, 0, stream>>>(ei, cursor, colidx);

    // encoder: Zf = x @ Ws + bs (f32), Zs = fp16 shadow (raw z, identity BN)
    gemm_mfma<false, false, false, true, false, false><<<gemmGrid, 256, 0, stream>>>(
        x, nullptr, nullptr, nullptr, WThi, WTlo, bs, Zf, Zs,
        nullptr, nullptr, nullptr);

    for (int l = 0; l < Ll; l++) {
        prep_layer<<<17, 256, 0, stream>>>(
            W1 + (size_t)l * 4096,
            stats + (l > 0 ? (l - 1) * 128 : 0),
            gamma + (l > 0 ? (l - 1) * 64 : 0),
            beta + (l > 0 ? (l - 1) * 64 : 0),
            WT1hi, WT1lo, shiftW1,
            sc5 + (l > 0 ? (l - 1) * 128 : 0), l);
        gather_agg_h<<<Nn / 32, 256, 0, stream>>>(rowptr, colidx, Zs, Gf);
        // Mf = relu( (z_self + agg_z) @ W1' + b1 + (1+deg)*shiftW1 )
        gemm_mfma<true, true, false, false, true, false><<<gemmGrid, 256, 0, stream>>>(
            Zf, Gf, rowptr, shiftW1, WT1hi, WT1lo, b1 + (size_t)l * 64,
            Mf, nullptr, nullptr, nullptr, nullptr);
        // z = relu(Mf @ W2 + b2) -> Zf/Zs, fused BN stats + per-graph pool
        gemm_mfma<false, true, true, true, false, true><<<gemmGrid, 256, 0, stream>>>(
            Mf, nullptr, nullptr, nullptr,
            WThi + (size_t)(1 + l) * 4096, WTlo + (size_t)(1 + l) * 4096,
            b2 + (size_t)l * 64, Zf, Zs, stats + (size_t)l * 128,
            batch, poolRaw + (size_t)l * Gg * 64);
    }

    final_pool<<<160, 256, 0, stream>>>(sc5, stats + 4 * 128, gamma, beta,
                                        poolRaw, cnt, pooled);

    // proj head (f32)
    proj<true><<<160, 256, 0, stream>>>(pooled, Wp1, bp1, ytmp);
    proj<false><<<160, 256, 0, stream>>>(ytmp, Wp2, bp2, ypro);

    l2norm_rows<<<Gg, 64, 0, stream>>>(ypro, out);               // out0
    l2norm_rows<<<Gg, 64, 0, stream>>>(pooled, out + Gg * PDim); // out1
}

// Round 10
// 775.461 us; speedup vs baseline: 1.2697x; 1.2697x over previous
//
#include <hip/hip_runtime.h>
#include <hip/hip_bf16.h>
#include <hip/hip_fp16.h>

constexpr int Nn = 100000;
constexpr int Ee = 1200000;
constexpr int Ll = 5;
constexpr int Gg = 128;
constexpr int PDim = 320; // L*D

// bucketed CSR build params
constexpr int NB    = 98;     // buckets of 1024 rows (dst >> 10)
constexpr int BCAP  = 16384;  // per-bucket edge capacity (mean 12288, 18 sigma safe)
constexpr int CHUNK = 4096;   // edges per bin_edges block
constexpr int NBLK_A = (Ee + CHUNK - 1) / CHUNK; // 293

typedef short short8 __attribute__((ext_vector_type(8)));
typedef float f32x4 __attribute__((ext_vector_type(4)));

union U4S8 { uint4 u; short8 s; };

__device__ inline ushort f2bf(float f) {
    const uint u = __float_as_uint(f);
    return (ushort)((u + 0x7fffu + ((u >> 16) & 1u)) >> 16);
}
__device__ inline uint pack2(float lo, float hi) {
    return (uint)f2bf(lo) | ((uint)f2bf(hi) << 16);
}
__device__ inline ushort f2h(float f) {
    const __half h = __float2half(f);
    return *(const ushort*)&h;
}
__device__ inline uint pack2h(float lo, float hi) {
    return (uint)f2h(lo) | ((uint)f2h(hi) << 16);
}
__device__ inline float h2f_lo(uint u) {
    const ushort s = (ushort)(u & 0xffffu);
    return __half2float(*(const __half*)&s);
}
__device__ inline float h2f_hi(uint u) {
    const ushort s = (ushort)(u >> 16);
    return __half2float(*(const __half*)&s);
}
// split x0,x1 into packed bf16 hi word + bf16 lo (residual) word
__device__ inline void split2(float x0, float x1, uint& hi, uint& lo) {
    const ushort h0 = f2bf(x0), h1 = f2bf(x1);
    hi = (uint)h0 | ((uint)h1 << 16);
    const float r0 = x0 - __uint_as_float((uint)h0 << 16);
    const float r1 = x1 - __uint_as_float((uint)h1 << 16);
    lo = pack2(r0, r1);
}

__device__ inline int lower_bound_i(const int* __restrict__ a, int n, int v)
{
    int lo = 0, hi = n;
    while (lo < hi) {
        const int m = (lo + hi) >> 1;
        if (a[m] < v) lo = m + 1; else hi = m;
    }
    return lo;
}

// ---------------------------------------------------------------------------
// Weight conversion: 11 64x64 f32 matrices -> TRANSPOSED bf16 hi/lo pair.
// Block m: 0=Ws, 1..5=W1[m-1], 6..10=W2[m-6].
// ---------------------------------------------------------------------------
__global__ __launch_bounds__(256) void conv_weights(
    const float* __restrict__ Ws, const float* __restrict__ W1,
    const float* __restrict__ W2, ushort* __restrict__ WThi,
    ushort* __restrict__ WTlo)
{
    const int m = blockIdx.x;
    const float* src = (m == 0) ? Ws
                     : (m <= 5) ? W1 + (size_t)(m - 1) * 4096
                                : W2 + (size_t)(m - 6) * 4096;
    ushort* dh = WThi + (size_t)m * 4096;
    ushort* dl = WTlo + (size_t)m * 4096;
    const int t = threadIdx.x;
    const int col = t & 63;
    const int k0 = (t >> 6) * 16;
    #pragma unroll
    for (int i = 0; i < 16; i++) {
        const int k = k0 + i;
        const float w = src[k * 64 + col];
        const ushort h = f2bf(w);
        dh[col * 64 + k] = h;
        dl[col * 64 + k] = f2bf(w - __uint_as_float((uint)h << 16));
    }
}

// ---------------------------------------------------------------------------
// Split-bf16 MFMA GEMM: Y = act(A (+A2) @ W + b), f32 in / f32 out.
// acc += Alo*Whi + Ahi*Wlo + Ahi*Whi (3 MFMA, f32-grade result).
// AMODE: 0 = A1 only; 1 = A1 + A2 (GIN sum).
// STATS: fused per-column sum/sumsq into stats[0:128].
// SHADOW: also write fp16 copy of output (for gather).
// ---------------------------------------------------------------------------
template<int AMODE, bool RELU, bool STATS, bool SHADOW>
__global__ __launch_bounds__(256) void gemm_mfma(
    const float* __restrict__ A1, const float* __restrict__ A2,
    const ushort* __restrict__ WThi, const ushort* __restrict__ WTlo,
    const float* __restrict__ bias, float* __restrict__ Y,
    ushort* __restrict__ Ys, float* __restrict__ stats)
{
    const int t = threadIdx.x;
    const int w = t >> 6;
    const int l = t & 63;
    const int lr = l & 15;   // A-row / B-col within tile
    const int lk = l >> 4;   // k-group (8 elems each)

    // B fragments: col = nt*16+lr, k = c*32 + lk*8 (contiguous in WT)
    short8 bHi[4][2], bLo[4][2];
    #pragma unroll
    for (int nt = 0; nt < 4; nt++)
        #pragma unroll
        for (int c = 0; c < 2; c++) {
            const int off = (nt * 16 + lr) * 64 + c * 32 + lk * 8;
            U4S8 uh, ul;
            uh.u = *(const uint4*)(WThi + off);
            ul.u = *(const uint4*)(WTlo + off);
            bHi[nt][c] = uh.s;
            bLo[nt][c] = ul.s;
        }

    // A fragments (NO early return: MFMA is wave-collective)
    const int arow = blockIdx.x * 64 + w * 16 + lr;
    short8 aHi[2], aLo[2];
    if (arow < Nn) {
        #pragma unroll
        for (int c = 0; c < 2; c++) {
            const int koff = c * 32 + lk * 8;
            const float* p1 = A1 + (size_t)arow * 64 + koff;
            float v[8];
            {
                const float4 v0 = *(const float4*)p1;
                const float4 v1 = *(const float4*)(p1 + 4);
                v[0] = v0.x; v[1] = v0.y; v[2] = v0.z; v[3] = v0.w;
                v[4] = v1.x; v[5] = v1.y; v[6] = v1.z; v[7] = v1.w;
            }
            if constexpr (AMODE == 1) {
                const float* p2 = A2 + (size_t)arow * 64 + koff;
                const float4 u0 = *(const float4*)p2;
                const float4 u1 = *(const float4*)(p2 + 4);
                v[0] += u0.x; v[1] += u0.y; v[2] += u0.z; v[3] += u0.w;
                v[4] += u1.x; v[5] += u1.y; v[6] += u1.z; v[7] += u1.w;
            }
            U4S8 rh, rl;
            uint* ph = (uint*)&rh.u;
            uint* pl = (uint*)&rl.u;
            #pragma unroll
            for (int i = 0; i < 4; i++)
                split2(v[2 * i], v[2 * i + 1], ph[i], pl[i]);
            aHi[c] = rh.s;
            aLo[c] = rl.s;
        }
    } else {
        U4S8 z; z.u = make_uint4(0, 0, 0, 0);
        aHi[0] = aHi[1] = z.s;
        aLo[0] = aLo[1] = z.s;
    }

    f32x4 acc[4] = {};
    #pragma unroll
    for (int nt = 0; nt < 4; nt++)
        #pragma unroll
        for (int c = 0; c < 2; c++) {
            acc[nt] = __builtin_amdgcn_mfma_f32_16x16x32_bf16(
                aLo[c], bHi[nt][c], acc[nt], 0, 0, 0);
            acc[nt] = __builtin_amdgcn_mfma_f32_16x16x32_bf16(
                aHi[c], bLo[nt][c], acc[nt], 0, 0, 0);
            acc[nt] = __builtin_amdgcn_mfma_f32_16x16x32_bf16(
                aHi[c], bHi[nt][c], acc[nt], 0, 0, 0);
        }

    // Epilogue: C/D layout col=lane&15, row=(lane>>4)*4+reg  [m89]
    float s[4], s2[4];
    #pragma unroll
    for (int nt = 0; nt < 4; nt++) {
        const int ccol = nt * 16 + lr;
        const float bb = bias[ccol];
        s[nt] = 0.f; s2[nt] = 0.f;
        #pragma unroll
        for (int j = 0; j < 4; j++) {
            const int crow = blockIdx.x * 64 + w * 16 + lk * 4 + j;
            if (crow < Nn) {
                float v = acc[nt][j] + bb;
                if constexpr (RELU) v = fmaxf(v, 0.f);
                Y[(size_t)crow * 64 + ccol] = v;
                if constexpr (SHADOW) Ys[(size_t)crow * 64 + ccol] = f2h(v);
                if constexpr (STATS) { s[nt] += v; s2[nt] += v * v; }
            }
        }
    }

    if constexpr (STATS) {
        #pragma unroll
        for (int nt = 0; nt < 4; nt++) {
            s[nt]  += __shfl_xor(s[nt], 16);  s[nt]  += __shfl_xor(s[nt], 32);
            s2[nt] += __shfl_xor(s2[nt], 16); s2[nt] += __shfl_xor(s2[nt], 32);
        }
        __shared__ float red[2][4][4][16]; // [s|s2][wave][nt][col16]
        if (l < 16) {
            #pragma unroll
            for (int nt = 0; nt < 4; nt++) {
                red[0][w][nt][l] = s[nt];
                red[1][w][nt][l] = s2[nt];
            }
        }
        __syncthreads();
        if (t < 64) { // column = (t>>4)*16 + (t&15) = t
            float ts = 0.f, ts2 = 0.f;
            #pragma unroll
            for (int wv = 0; wv < 4; wv++) {
                ts  += red[0][wv][t >> 4][t & 15];
                ts2 += red[1][wv][t >> 4][t & 15];
            }
            atomicAdd(&stats[t], ts);
            atomicAdd(&stats[64 + t], ts2);
        }
    }
}

// ---------------------------------------------------------------------------
// Bucketed CSR build.
// ---------------------------------------------------------------------------
__global__ void init_csr(int* __restrict__ gCursor)
{
    const int t = threadIdx.x;
    if (t < NB) gCursor[t] = t * BCAP;
}

// Phase A: bin edges into NB fixed-capacity bucket regions (by dst>>10).
__global__ __launch_bounds__(256) void bin_edges(
    const int* __restrict__ ei, int* __restrict__ gCursor,
    uint2* __restrict__ binned)
{
    __shared__ int hist[NB];
    __shared__ int base[NB];
    __shared__ int cur[NB];
    const int t = threadIdx.x;
    const int e0 = blockIdx.x * CHUNK;
    const int eEnd = min(e0 + CHUNK, Ee);
    if (t < NB) hist[t] = 0;
    __syncthreads();
    for (int e = e0 + t; e < eEnd; e += 256)
        atomicAdd(&hist[ei[Ee + e] >> 10], 1);
    __syncthreads();
    if (t < NB) {
        base[t] = atomicAdd(&gCursor[t], hist[t]);
        cur[t] = 0;
    }
    __syncthreads();
    for (int e = e0 + t; e < eEnd; e += 256) {
        const int s = ei[e];
        const int d = ei[Ee + e];
        const int b = d >> 10;
        const int pos = atomicAdd(&cur[b], 1);
        binned[(size_t)base[b] + pos] = make_uint2((uint)d, (uint)s);
    }
}

// bucket counts -> exclusive scan (1 block)
__global__ __launch_bounds__(128) void scan_buckets(
    const int* __restrict__ gCursor, int* __restrict__ bucketBase)
{
    __shared__ int sh[128];
    const int t = threadIdx.x;
    const int c = (t < NB) ? gCursor[t] - t * BCAP : 0;
    sh[t] = c;
    __syncthreads();
    for (int off = 1; off < 128; off <<= 1) {
        const int u = (t >= off) ? sh[t - off] : 0;
        __syncthreads();
        sh[t] += u;
        __syncthreads();
    }
    bucketBase[t] = sh[t] - c; // exclusive
}

// Phase B: per bucket, LDS histogram + scan + LDS colStage scatter,
// sequential rowptr/colidx writes. 69KB LDS.
__global__ __launch_bounds__(256) void build_csr(
    const uint2* __restrict__ binned, const int* __restrict__ gCursor,
    const int* __restrict__ bucketBase, int* __restrict__ rowptr,
    int* __restrict__ colidx)
{
    __shared__ int degS[1024];
    __shared__ int sh[256];
    __shared__ int colStage[BCAP];
    const int b = blockIdx.x;
    const int t = threadIdx.x;
    const int cnt = gCursor[b] - b * BCAP;
    const int base = bucketBase[b];
    const uint2* src = binned + (size_t)b * BCAP;

    for (int i = t; i < 1024; i += 256) degS[i] = 0;
    __syncthreads();
    for (int i = t; i < cnt; i += 256)
        atomicAdd(&degS[src[i].x & 1023], 1);
    __syncthreads();

    // exclusive scan of degS[1024]: 4 elems per thread + block scan
    const int b4 = t * 4;
    const int v0 = degS[b4], v1 = degS[b4 + 1], v2 = degS[b4 + 2], v3 = degS[b4 + 3];
    const int sSum = v0 + v1 + v2 + v3;
    sh[t] = sSum;
    __syncthreads();
    for (int off = 1; off < 256; off <<= 1) {
        const int u = (t >= off) ? sh[t - off] : 0;
        __syncthreads();
        sh[t] += u;
        __syncthreads();
    }
    const int excl = sh[t] - sSum;
    const int p0 = excl, p1 = excl + v0, p2 = excl + v0 + v1, p3 = excl + v0 + v1 + v2;

    // write rowptr (global rows b*1024 + b4 .. +3); guard tail past Nn
    const int grow = b * 1024 + b4;
    if (grow + 3 <= Nn) {
        *(int4*)(rowptr + grow) = make_int4(base + p0, base + p1, base + p2, base + p3);
    } else {
        if (grow + 0 <= Nn) rowptr[grow + 0] = base + p0;
        if (grow + 1 <= Nn) rowptr[grow + 1] = base + p1;
        if (grow + 2 <= Nn) rowptr[grow + 2] = base + p2;
        if (grow + 3 <= Nn) rowptr[grow + 3] = base + p3;
    }

    // degS becomes the running cursor
    degS[b4] = p0; degS[b4 + 1] = p1; degS[b4 + 2] = p2; degS[b4 + 3] = p3;
    __syncthreads();
    for (int i = t; i < cnt; i += 256) {
        const uint2 p = src[i];
        const int pos = atomicAdd(&degS[p.x & 1023], 1);
        colStage[pos] = (int)p.y;
    }
    __syncthreads();
    for (int i = t; i < cnt; i += 256) colidx[base + i] = colStage[i];
}

// ---------------------------------------------------------------------------
// Pull aggregation: agg[r] (f32) = sum_{j in row r} hs[col[j]] (fp16 shadow).
// 8 lanes per row (uint4 = 8 fp16 each), 32 rows per block. Grid exact.
// ---------------------------------------------------------------------------
__global__ __launch_bounds__(256) void gather_agg_h(
    const int* __restrict__ rowptr, const int* __restrict__ col,
    const ushort* __restrict__ hs, float* __restrict__ agg)
{
    const int r = blockIdx.x * 32 + (threadIdx.x >> 3);
    const int q = threadIdx.x & 7;
    const int beg = rowptr[r], end = rowptr[r + 1];
    float a[8] = {};
    for (int j = beg; j < end; j++) {
        const int s = col[j];
        const uint4 v = *(const uint4*)(hs + (size_t)s * 64 + q * 8);
        a[0] += h2f_lo(v.x); a[1] += h2f_hi(v.x);
        a[2] += h2f_lo(v.y); a[3] += h2f_hi(v.y);
        a[4] += h2f_lo(v.z); a[5] += h2f_hi(v.z);
        a[6] += h2f_lo(v.w); a[7] += h2f_hi(v.w);
    }
    float* o = agg + (size_t)r * 64 + q * 8;
    *(float4*)o       = make_float4(a[0], a[1], a[2], a[3]);
    *(float4*)(o + 4) = make_float4(a[4], a[5], a[6], a[7]);
}

// Compute scale/shift from stats, then zero stats for the next layer.
__global__ void bn_finalize(
    float* __restrict__ stats, const float* __restrict__ gamma,
    const float* __restrict__ beta, float* __restrict__ sc, int layer)
{
    const int c = threadIdx.x; // 64 threads, 1 block
    const float mean = stats[c] * (1.0f / Nn);
    const float var = stats[64 + c] * (1.0f / Nn) - mean * mean;
    const float scale = gamma[layer * 64 + c] * rsqrtf(var + 1e-5f);
    sc[c] = scale;
    sc[64 + c] = beta[layer * 64 + c] - mean * scale;
    stats[c] = 0.f;
    stats[64 + c] = 0.f;
}

// ---------------------------------------------------------------------------
// Apply BN in place (f32), write fp16 shadow, accumulate per-graph pooled
// sums (f32). 8 blocks per graph; batch is sorted.
// ---------------------------------------------------------------------------
__global__ __launch_bounds__(256) void bn_apply_pool(
    float* __restrict__ z, ushort* __restrict__ zs,
    const int* __restrict__ batch, const float* __restrict__ sc,
    float* __restrict__ pooled, int layer)
{
    const int g = blockIdx.x >> 3;
    const int sub = blockIdx.x & 7;
    const int lo = lower_bound_i(batch, Nn, g);
    const int hi = lower_bound_i(batch, Nn, g + 1);
    const int t = threadIdx.x;
    const int cq = t & 15;                 // cols cq*4 .. +3
    const int rg = (t >> 4) + sub * 16;    // 0..127
    float scl[4], sft[4], acc[4] = {};
    #pragma unroll
    for (int i = 0; i < 4; i++) {
        scl[i] = sc[cq * 4 + i];
        sft[i] = sc[64 + cq * 4 + i];
    }
    for (int row = lo + rg; row < hi; row += 128) {
        float4 v = *(float4*)(z + (size_t)row * 64 + cq * 4);
        v.x = fmaf(scl[0], v.x, sft[0]);
        v.y = fmaf(scl[1], v.y, sft[1]);
        v.z = fmaf(scl[2], v.z, sft[2]);
        v.w = fmaf(scl[3], v.w, sft[3]);
        *(float4*)(z + (size_t)row * 64 + cq * 4) = v;
        uint2 p;
        p.x = pack2h(v.x, v.y);
        p.y = pack2h(v.z, v.w);
        *(uint2*)(zs + (size_t)row * 64 + cq * 4) = p;
        acc[0] += v.x; acc[1] += v.y; acc[2] += v.z; acc[3] += v.w;
    }
    __shared__ float red[16][16][4];
    #pragma unroll
    for (int i = 0; i < 4; i++) red[t >> 4][cq][i] = acc[i];
    __syncthreads();
    if (t < 64) {
        const int c2 = t >> 2, j = t & 3;
        float s = 0.f;
        #pragma unroll
        for (int r = 0; r < 16; r++) s += red[r][c2][j];
        atomicAdd(&pooled[g * PDim + layer * 64 + c2 * 4 + j], s);
    }
}

// ---------------------------------------------------------------------------
// Proj head GEMM: (128,320)@(320,320)+b (f32, small).
// ---------------------------------------------------------------------------
template<bool RELU>
__global__ __launch_bounds__(256) void proj(
    const float* __restrict__ X, const float* __restrict__ W,
    const float* __restrict__ bias, float* __restrict__ Y)
{
    const int idx = blockIdx.x * 256 + threadIdx.x; // 40960 exact
    const int r = idx / PDim;
    const int c = idx - r * PDim;
    float acc = bias[c];
    #pragma unroll 8
    for (int k = 0; k < PDim; k++)
        acc = fmaf(X[r * PDim + k], W[k * PDim + c], acc);
    if constexpr (RELU) acc = fmaxf(acc, 0.f);
    Y[idx] = acc;
}

// ---------------------------------------------------------------------------
// Row-wise l2 normalize.
// ---------------------------------------------------------------------------
__global__ __launch_bounds__(64) void l2norm_rows(
    const float* __restrict__ X, float* __restrict__ out)
{
    const int r = blockIdx.x;
    const int l = threadIdx.x;
    float v[5];
    float s = 0.f;
    #pragma unroll
    for (int i = 0; i < 5; i++) {
        v[i] = X[r * PDim + i * 64 + l];
        s += v[i] * v[i];
    }
    #pragma unroll
    for (int off = 32; off > 0; off >>= 1) s += __shfl_down(s, off);
    s = __shfl(s, 0);
    const float d = fmaxf(sqrtf(s), 1e-12f);
    #pragma unroll
    for (int i = 0; i < 5; i++)
        out[r * PDim + i * 64 + l] = v[i] / d;
}

// ---------------------------------------------------------------------------
extern "C" void kernel_launch(void* const* d_in, const int* in_sizes, int n_in,
                              void* d_out, int out_size, void* d_ws, size_t ws_size,
                              hipStream_t stream)
{
    const float* x     = (const float*)d_in[0];
    const int*   ei    = (const int*)d_in[1];
    const int*   batch = (const int*)d_in[2];
    const float* Ws    = (const float*)d_in[3];
    const float* bs    = (const float*)d_in[4];
    const float* W1    = (const float*)d_in[5];
    const float* b1    = (const float*)d_in[6];
    const float* W2    = (const float*)d_in[7];
    const float* b2    = (const float*)d_in[8];
    const float* gamma = (const float*)d_in[9];
    const float* beta  = (const float*)d_in[10];
    const float* Wp1   = (const float*)d_in[11];
    const float* bp1   = (const float*)d_in[12];
    const float* Wp2   = (const float*)d_in[13];
    const float* bp2   = (const float*)d_in[14];
    float* out = (float*)d_out;

    // workspace (big 16B-aligned arrays first)
    float*  Hf  = (float*)d_ws;                   // h f32 (N*64)      25.6MB
    float*  Gf  = Hf + (size_t)Nn * 64;           // agg f32           25.6MB
    float*  Zf  = Gf + (size_t)Nn * 64;           // z1 f32            25.6MB
    ushort* Hs  = (ushort*)(Zf + (size_t)Nn * 64);// h fp16 shadow     12.8MB
    ushort* WThi = Hs + (size_t)Nn * 64;          // 11*4096 bf16
    ushort* WTlo = WThi + 11 * 4096;
    float* pooled = (float*)(WTlo + 11 * 4096);   // (G,320)
    float* ytmp   = pooled + (size_t)Gg * PDim;
    float* ypro   = ytmp + (size_t)Gg * PDim;
    float* stats  = ypro + (size_t)Gg * PDim;     // 128
    float* sc     = stats + 128;                  // 128
    int* rowptr = (int*)(sc + 128);               // Nn+1
    int* colidx = rowptr + Nn + 1;                // Ee
    int* gCursor = colidx + Ee;                   // 128 (NB used)
    int* bucketBase = gCursor + 128;              // 128
    // 8B-align for uint2 binned
    size_t woff = (size_t)((bucketBase + 128) - (int*)d_ws);
    woff = (woff + 1) & ~(size_t)1;
    uint2* binned = (uint2*)((int*)d_ws + woff);  // NB*BCAP*8B = 12.6MB

    const int gemmGrid = (Nn + 63) / 64;          // 1563

    hipMemsetAsync(stats, 0, 128 * sizeof(float), stream);
    hipMemsetAsync(pooled, 0, (size_t)Gg * PDim * sizeof(float), stream);

    conv_weights<<<11, 256, 0, stream>>>(Ws, W1, W2, WThi, WTlo);

    // bucketed CSR build
    init_csr<<<1, 128, 0, stream>>>(gCursor);
    bin_edges<<<NBLK_A, 256, 0, stream>>>(ei, gCursor, binned);
    scan_buckets<<<1, 128, 0, stream>>>(gCursor, bucketBase);
    build_csr<<<NB, 256, 0, stream>>>(binned, gCursor, bucketBase, rowptr, colidx);

    // encoder: Hf = x @ Ws + bs (f32), Hs = fp16 shadow
    gemm_mfma<0, false, false, true><<<gemmGrid, 256, 0, stream>>>(
        x, nullptr, WThi, WTlo, bs, Hf, Hs, nullptr);

    for (int l = 0; l < Ll; l++) {
        gather_agg_h<<<Nn / 32, 256, 0, stream>>>(rowptr, colidx, Hs, Gf);
        // z1 = relu((h+agg)@W1+b1) -> Zf (f32)
        gemm_mfma<1, true, false, false><<<gemmGrid, 256, 0, stream>>>(
            Hf, Gf, WThi + (size_t)(1 + l) * 4096, WTlo + (size_t)(1 + l) * 4096,
            b1 + (size_t)l * 64, Zf, nullptr, nullptr);
        // z2 = relu(z1@W2+b2) -> Hf (f32), fused BN stats
        gemm_mfma<0, true, true, false><<<gemmGrid, 256, 0, stream>>>(
            Zf, nullptr, WThi + (size_t)(6 + l) * 4096, WTlo + (size_t)(6 + l) * 4096,
            b2 + (size_t)l * 64, Hf, nullptr, stats);
        bn_finalize<<<1, 64, 0, stream>>>(stats, gamma, beta, sc, l);
        bn_apply_pool<<<Gg * 8, 256, 0, stream>>>(Hf, Hs, batch, sc, pooled, l);
    }

    // proj head (f32)
    proj<true><<<160, 256, 0, stream>>>(pooled, Wp1, bp1, ytmp);
    proj<false><<<160, 256, 0, stream>>>(ytmp, Wp2, bp2, ypro);

    l2norm_rows<<<Gg, 64, 0, stream>>>(ypro, out);               // out0
    l2norm_rows<<<Gg, 64, 0, stream>>>(pooled, out + Gg * PDim); // out1
}

// Round 11
// 668.217 us; speedup vs baseline: 1.4735x; 1.1605x over previous
//
#include <hip/hip_runtime.h>
#include <hip/hip_bf16.h>
#include <hip/hip_fp16.h>

constexpr int Nn = 100000;
constexpr int Ee = 1200000;
constexpr int Ll = 5;
constexpr int Gg = 128;
constexpr int PDim = 320; // L*D

// bucketed CSR build params
constexpr int NB    = 98;     // buckets of 1024 rows (dst >> 10)
constexpr int BCAP  = 16384;  // per-bucket edge capacity
constexpr int CHUNK = 4096;   // edges per bin_edges block
constexpr int NBLK_A = (Ee + CHUNK - 1) / CHUNK; // 293

typedef short short8 __attribute__((ext_vector_type(8)));
typedef float f32x4 __attribute__((ext_vector_type(4)));

union U4S8 { uint4 u; short8 s; };

__device__ inline ushort f2bf(float f) {
    const uint u = __float_as_uint(f);
    return (ushort)((u + 0x7fffu + ((u >> 16) & 1u)) >> 16);
}
__device__ inline uint pack2(float lo, float hi) {
    return (uint)f2bf(lo) | ((uint)f2bf(hi) << 16);
}
__device__ inline ushort f2h(float f) {
    const __half h = __float2half(f);
    return *(const ushort*)&h;
}
__device__ inline uint pack2h(float lo, float hi) {
    return (uint)f2h(lo) | ((uint)f2h(hi) << 16);
}
__device__ inline float h2f_lo(uint u) {
    const ushort s = (ushort)(u & 0xffffu);
    return __half2float(*(const __half*)&s);
}
__device__ inline float h2f_hi(uint u) {
    const ushort s = (ushort)(u >> 16);
    return __half2float(*(const __half*)&s);
}
// split x0,x1 into packed bf16 hi word + bf16 lo (residual) word
__device__ inline void split2(float x0, float x1, uint& hi, uint& lo) {
    const ushort h0 = f2bf(x0), h1 = f2bf(x1);
    hi = (uint)h0 | ((uint)h1 << 16);
    const float r0 = x0 - __uint_as_float((uint)h0 << 16);
    const float r1 = x1 - __uint_as_float((uint)h1 << 16);
    lo = pack2(r0, r1);
}

__device__ inline int lower_bound_i(const int* __restrict__ a, int n, int v)
{
    int lo = 0, hi = n;
    while (lo < hi) {
        const int m = (lo + hi) >> 1;
        if (a[m] < v) lo = m + 1; else hi = m;
    }
    return lo;
}

// ---------------------------------------------------------------------------
// Weight conversion: 11 64x64 f32 matrices -> TRANSPOSED bf16 hi/lo pair.
// Block m: 0=Ws, 1..5=W1[m-1], 6..10=W2[m-6].
// ---------------------------------------------------------------------------
__global__ __launch_bounds__(256) void conv_weights(
    const float* __restrict__ Ws, const float* __restrict__ W1,
    const float* __restrict__ W2, ushort* __restrict__ WThi,
    ushort* __restrict__ WTlo)
{
    const int m = blockIdx.x;
    const float* src = (m == 0) ? Ws
                     : (m <= 5) ? W1 + (size_t)(m - 1) * 4096
                                : W2 + (size_t)(m - 6) * 4096;
    ushort* dh = WThi + (size_t)m * 4096;
    ushort* dl = WTlo + (size_t)m * 4096;
    const int t = threadIdx.x;
    const int col = t & 63;
    const int k0 = (t >> 6) * 16;
    #pragma unroll
    for (int i = 0; i < 16; i++) {
        const int k = k0 + i;
        const float w = src[k * 64 + col];
        const ushort h = f2bf(w);
        dh[col * 64 + k] = h;
        dl[col * 64 + k] = f2bf(w - __uint_as_float((uint)h << 16));
    }
}

// ---------------------------------------------------------------------------
// Encoder GEMM: Hs = fp16(x @ Ws + bs). Split-bf16 MFMA, fp16-shadow-only out.
// ---------------------------------------------------------------------------
__global__ __launch_bounds__(256) void gemm_enc(
    const float* __restrict__ A1,
    const ushort* __restrict__ WThi, const ushort* __restrict__ WTlo,
    const float* __restrict__ bias, ushort* __restrict__ Ys)
{
    const int t = threadIdx.x;
    const int w = t >> 6;
    const int l = t & 63;
    const int lr = l & 15;
    const int lk = l >> 4;

    short8 bHi[4][2], bLo[4][2];
    #pragma unroll
    for (int nt = 0; nt < 4; nt++)
        #pragma unroll
        for (int c = 0; c < 2; c++) {
            const int off = (nt * 16 + lr) * 64 + c * 32 + lk * 8;
            U4S8 uh, ul;
            uh.u = *(const uint4*)(WThi + off);
            ul.u = *(const uint4*)(WTlo + off);
            bHi[nt][c] = uh.s;
            bLo[nt][c] = ul.s;
        }

    const int arow = blockIdx.x * 64 + w * 16 + lr;
    short8 aHi[2], aLo[2];
    if (arow < Nn) {
        #pragma unroll
        for (int c = 0; c < 2; c++) {
            const float* p1 = A1 + (size_t)arow * 64 + c * 32 + lk * 8;
            const float4 v0 = *(const float4*)p1;
            const float4 v1 = *(const float4*)(p1 + 4);
            U4S8 rh, rl;
            uint* ph = (uint*)&rh.u;
            uint* pl = (uint*)&rl.u;
            split2(v0.x, v0.y, ph[0], pl[0]);
            split2(v0.z, v0.w, ph[1], pl[1]);
            split2(v1.x, v1.y, ph[2], pl[2]);
            split2(v1.z, v1.w, ph[3], pl[3]);
            aHi[c] = rh.s;
            aLo[c] = rl.s;
        }
    } else {
        U4S8 z; z.u = make_uint4(0, 0, 0, 0);
        aHi[0] = aHi[1] = z.s;
        aLo[0] = aLo[1] = z.s;
    }

    f32x4 acc[4] = {};
    #pragma unroll
    for (int nt = 0; nt < 4; nt++)
        #pragma unroll
        for (int c = 0; c < 2; c++) {
            acc[nt] = __builtin_amdgcn_mfma_f32_16x16x32_bf16(
                aLo[c], bHi[nt][c], acc[nt], 0, 0, 0);
            acc[nt] = __builtin_amdgcn_mfma_f32_16x16x32_bf16(
                aHi[c], bLo[nt][c], acc[nt], 0, 0, 0);
            acc[nt] = __builtin_amdgcn_mfma_f32_16x16x32_bf16(
                aHi[c], bHi[nt][c], acc[nt], 0, 0, 0);
        }

    #pragma unroll
    for (int nt = 0; nt < 4; nt++) {
        const int ccol = nt * 16 + lr;
        const float bb = bias[ccol];
        #pragma unroll
        for (int j = 0; j < 4; j++) {
            const int crow = blockIdx.x * 64 + w * 16 + lk * 4 + j;
            if (crow < Nn)
                Ys[(size_t)crow * 64 + ccol] = f2h(acc[nt][j] + bb);
        }
    }
}

// ---------------------------------------------------------------------------
// Fused GIN MLP: z = relu(relu(u@W1+b1)@W2+b2), u f32 in, z f32 out,
// fused per-column BN stats. M never leaves the block: wave w's stage-1
// output rows (w*16..+16) are its own stage-2 A rows (row-parallel GEMMs).
// LDS M stored as padded [64][72] bf16 hi/lo (2-way bank conflict max).
// ---------------------------------------------------------------------------
__global__ __launch_bounds__(256) void fused_mlp(
    const float* __restrict__ Uf,
    const ushort* __restrict__ WT1hi, const ushort* __restrict__ WT1lo,
    const float* __restrict__ b1v,
    const ushort* __restrict__ WT2hi, const ushort* __restrict__ WT2lo,
    const float* __restrict__ b2v,
    float* __restrict__ Z, float* __restrict__ stats)
{
    const int t = threadIdx.x;
    const int w = t >> 6;
    const int l = t & 63;
    const int lr = l & 15;   // A-row / B-col within 16-tile
    const int lk = l >> 4;   // k-group (8 elems each)

    __shared__ ushort Mhi[64][72];
    __shared__ ushort Mlo[64][72];
    __shared__ float red[2][4][4][16];

    // ---- stage 1: M = relu(u @ W1 + b1) ----
    short8 b1Hi[4][2], b1Lo[4][2];
    #pragma unroll
    for (int nt = 0; nt < 4; nt++)
        #pragma unroll
        for (int c = 0; c < 2; c++) {
            const int off = (nt * 16 + lr) * 64 + c * 32 + lk * 8;
            U4S8 uh, ul;
            uh.u = *(const uint4*)(WT1hi + off);
            ul.u = *(const uint4*)(WT1lo + off);
            b1Hi[nt][c] = uh.s;
            b1Lo[nt][c] = ul.s;
        }

    const int arow = blockIdx.x * 64 + w * 16 + lr;
    short8 aHi[2], aLo[2];
    if (arow < Nn) {
        #pragma unroll
        for (int c = 0; c < 2; c++) {
            const float* p1 = Uf + (size_t)arow * 64 + c * 32 + lk * 8;
            const float4 v0 = *(const float4*)p1;
            const float4 v1 = *(const float4*)(p1 + 4);
            U4S8 rh, rl;
            uint* ph = (uint*)&rh.u;
            uint* pl = (uint*)&rl.u;
            split2(v0.x, v0.y, ph[0], pl[0]);
            split2(v0.z, v0.w, ph[1], pl[1]);
            split2(v1.x, v1.y, ph[2], pl[2]);
            split2(v1.z, v1.w, ph[3], pl[3]);
            aHi[c] = rh.s;
            aLo[c] = rl.s;
        }
    } else {
        U4S8 z; z.u = make_uint4(0, 0, 0, 0);
        aHi[0] = aHi[1] = z.s;
        aLo[0] = aLo[1] = z.s;
    }

    f32x4 acc[4] = {};
    #pragma unroll
    for (int nt = 0; nt < 4; nt++)
        #pragma unroll
        for (int c = 0; c < 2; c++) {
            acc[nt] = __builtin_amdgcn_mfma_f32_16x16x32_bf16(
                aLo[c], b1Hi[nt][c], acc[nt], 0, 0, 0);
            acc[nt] = __builtin_amdgcn_mfma_f32_16x16x32_bf16(
                aHi[c], b1Lo[nt][c], acc[nt], 0, 0, 0);
            acc[nt] = __builtin_amdgcn_mfma_f32_16x16x32_bf16(
                aHi[c], b1Hi[nt][c], acc[nt], 0, 0, 0);
        }

    // M -> LDS (bf16 hi/lo); C/D layout: row = lk*4+j, col = nt*16+lr [m89]
    #pragma unroll
    for (int nt = 0; nt < 4; nt++) {
        const int ccol = nt * 16 + lr;
        const float bb = b1v[ccol];
        #pragma unroll
        for (int j = 0; j < 4; j++) {
            const int rloc = w * 16 + lk * 4 + j;
            const float m = fmaxf(acc[nt][j] + bb, 0.f);
            const ushort h = f2bf(m);
            Mhi[rloc][ccol] = h;
            Mlo[rloc][ccol] = f2bf(m - __uint_as_float((uint)h << 16));
        }
    }
    __syncthreads();

    // ---- stage 2: z = relu(M @ W2 + b2) ----
    short8 b2Hi[4][2], b2Lo[4][2];
    #pragma unroll
    for (int nt = 0; nt < 4; nt++)
        #pragma unroll
        for (int c = 0; c < 2; c++) {
            const int off = (nt * 16 + lr) * 64 + c * 32 + lk * 8;
            U4S8 uh, ul;
            uh.u = *(const uint4*)(WT2hi + off);
            ul.u = *(const uint4*)(WT2lo + off);
            b2Hi[nt][c] = uh.s;
            b2Lo[nt][c] = ul.s;
        }

    short8 a2Hi[2], a2Lo[2];
    #pragma unroll
    for (int c = 0; c < 2; c++) {
        U4S8 uh, ul;
        uh.u = *(const uint4*)&Mhi[w * 16 + lr][c * 32 + lk * 8];
        ul.u = *(const uint4*)&Mlo[w * 16 + lr][c * 32 + lk * 8];
        a2Hi[c] = uh.s;
        a2Lo[c] = ul.s;
    }

    f32x4 acc2[4] = {};
    #pragma unroll
    for (int nt = 0; nt < 4; nt++)
        #pragma unroll
        for (int c = 0; c < 2; c++) {
            acc2[nt] = __builtin_amdgcn_mfma_f32_16x16x32_bf16(
                a2Lo[c], b2Hi[nt][c], acc2[nt], 0, 0, 0);
            acc2[nt] = __builtin_amdgcn_mfma_f32_16x16x32_bf16(
                a2Hi[c], b2Lo[nt][c], acc2[nt], 0, 0, 0);
            acc2[nt] = __builtin_amdgcn_mfma_f32_16x16x32_bf16(
                a2Hi[c], b2Hi[nt][c], acc2[nt], 0, 0, 0);
        }

    float s[4], s2[4];
    #pragma unroll
    for (int nt = 0; nt < 4; nt++) {
        const int ccol = nt * 16 + lr;
        const float bb = b2v[ccol];
        s[nt] = 0.f; s2[nt] = 0.f;
        #pragma unroll
        for (int j = 0; j < 4; j++) {
            const int crow = blockIdx.x * 64 + w * 16 + lk * 4 + j;
            if (crow < Nn) {
                const float v = fmaxf(acc2[nt][j] + bb, 0.f);
                Z[(size_t)crow * 64 + ccol] = v;
                s[nt] += v; s2[nt] += v * v;
            }
        }
    }

    #pragma unroll
    for (int nt = 0; nt < 4; nt++) {
        s[nt]  += __shfl_xor(s[nt], 16);  s[nt]  += __shfl_xor(s[nt], 32);
        s2[nt] += __shfl_xor(s2[nt], 16); s2[nt] += __shfl_xor(s2[nt], 32);
    }
    if (l < 16) {
        #pragma unroll
        for (int nt = 0; nt < 4; nt++) {
            red[0][w][nt][l] = s[nt];
            red[1][w][nt][l] = s2[nt];
        }
    }
    __syncthreads();
    if (t < 64) { // column = (t>>4)*16 + (t&15) = t
        float ts = 0.f, ts2 = 0.f;
        #pragma unroll
        for (int wv = 0; wv < 4; wv++) {
            ts  += red[0][wv][t >> 4][t & 15];
            ts2 += red[1][wv][t >> 4][t & 15];
        }
        atomicAdd(&stats[t], ts);
        atomicAdd(&stats[64 + t], ts2);
    }
}

// ---------------------------------------------------------------------------
// Bucketed CSR build.
// ---------------------------------------------------------------------------
__global__ void init_csr(int* __restrict__ gCursor)
{
    const int t = threadIdx.x;
    if (t < NB) gCursor[t] = t * BCAP;
}

__global__ __launch_bounds__(256) void bin_edges(
    const int* __restrict__ ei, int* __restrict__ gCursor,
    uint2* __restrict__ binned)
{
    __shared__ int hist[NB];
    __shared__ int base[NB];
    __shared__ int cur[NB];
    const int t = threadIdx.x;
    const int e0 = blockIdx.x * CHUNK;
    const int eEnd = min(e0 + CHUNK, Ee);
    if (t < NB) hist[t] = 0;
    __syncthreads();
    for (int e = e0 + t; e < eEnd; e += 256)
        atomicAdd(&hist[ei[Ee + e] >> 10], 1);
    __syncthreads();
    if (t < NB) {
        base[t] = atomicAdd(&gCursor[t], hist[t]);
        cur[t] = 0;
    }
    __syncthreads();
    for (int e = e0 + t; e < eEnd; e += 256) {
        const int s = ei[e];
        const int d = ei[Ee + e];
        const int b = d >> 10;
        const int pos = atomicAdd(&cur[b], 1);
        binned[(size_t)base[b] + pos] = make_uint2((uint)d, (uint)s);
    }
}

__global__ __launch_bounds__(128) void scan_buckets(
    const int* __restrict__ gCursor, int* __restrict__ bucketBase)
{
    __shared__ int sh[128];
    const int t = threadIdx.x;
    const int c = (t < NB) ? gCursor[t] - t * BCAP : 0;
    sh[t] = c;
    __syncthreads();
    for (int off = 1; off < 128; off <<= 1) {
        const int u = (t >= off) ? sh[t - off] : 0;
        __syncthreads();
        sh[t] += u;
        __syncthreads();
    }
    bucketBase[t] = sh[t] - c; // exclusive
}

__global__ __launch_bounds__(256) void build_csr(
    const uint2* __restrict__ binned, const int* __restrict__ gCursor,
    const int* __restrict__ bucketBase, int* __restrict__ rowptr,
    int* __restrict__ colidx)
{
    __shared__ int degS[1024];
    __shared__ int sh[256];
    __shared__ int colStage[BCAP];
    const int b = blockIdx.x;
    const int t = threadIdx.x;
    const int cnt = gCursor[b] - b * BCAP;
    const int base = bucketBase[b];
    const uint2* src = binned + (size_t)b * BCAP;

    for (int i = t; i < 1024; i += 256) degS[i] = 0;
    __syncthreads();
    for (int i = t; i < cnt; i += 256)
        atomicAdd(&degS[src[i].x & 1023], 1);
    __syncthreads();

    const int b4 = t * 4;
    const int v0 = degS[b4], v1 = degS[b4 + 1], v2 = degS[b4 + 2], v3 = degS[b4 + 3];
    const int sSum = v0 + v1 + v2 + v3;
    sh[t] = sSum;
    __syncthreads();
    for (int off = 1; off < 256; off <<= 1) {
        const int u = (t >= off) ? sh[t - off] : 0;
        __syncthreads();
        sh[t] += u;
        __syncthreads();
    }
    const int excl = sh[t] - sSum;
    const int p0 = excl, p1 = excl + v0, p2 = excl + v0 + v1, p3 = excl + v0 + v1 + v2;

    const int grow = b * 1024 + b4;
    if (grow + 3 <= Nn) {
        *(int4*)(rowptr + grow) = make_int4(base + p0, base + p1, base + p2, base + p3);
    } else {
        if (grow + 0 <= Nn) rowptr[grow + 0] = base + p0;
        if (grow + 1 <= Nn) rowptr[grow + 1] = base + p1;
        if (grow + 2 <= Nn) rowptr[grow + 2] = base + p2;
        if (grow + 3 <= Nn) rowptr[grow + 3] = base + p3;
    }

    degS[b4] = p0; degS[b4 + 1] = p1; degS[b4 + 2] = p2; degS[b4 + 3] = p3;
    __syncthreads();
    for (int i = t; i < cnt; i += 256) {
        const uint2 p = src[i];
        const int pos = atomicAdd(&degS[p.x & 1023], 1);
        colStage[pos] = (int)p.y;
    }
    __syncthreads();
    for (int i = t; i < cnt; i += 256) colidx[base + i] = colStage[i];
}

// ---------------------------------------------------------------------------
// Inclusive pull aggregation: u[r] (f32) = hs[r] + sum_{j in row r} hs[col[j]].
// 8 lanes per row (uint4 = 8 fp16 each), 32 rows per block. Grid exact.
// ---------------------------------------------------------------------------
__global__ __launch_bounds__(256) void gather_agg_inc(
    const int* __restrict__ rowptr, const int* __restrict__ col,
    const ushort* __restrict__ hs, float* __restrict__ u)
{
    const int r = blockIdx.x * 32 + (threadIdx.x >> 3);
    const int q = threadIdx.x & 7;
    const int beg = rowptr[r], end = rowptr[r + 1];
    float a[8];
    {
        const uint4 v = *(const uint4*)(hs + (size_t)r * 64 + q * 8); // self
        a[0] = h2f_lo(v.x); a[1] = h2f_hi(v.x);
        a[2] = h2f_lo(v.y); a[3] = h2f_hi(v.y);
        a[4] = h2f_lo(v.z); a[5] = h2f_hi(v.z);
        a[6] = h2f_lo(v.w); a[7] = h2f_hi(v.w);
    }
    for (int j = beg; j < end; j++) {
        const int s = col[j];
        const uint4 v = *(const uint4*)(hs + (size_t)s * 64 + q * 8);
        a[0] += h2f_lo(v.x); a[1] += h2f_hi(v.x);
        a[2] += h2f_lo(v.y); a[3] += h2f_hi(v.y);
        a[4] += h2f_lo(v.z); a[5] += h2f_hi(v.z);
        a[6] += h2f_lo(v.w); a[7] += h2f_hi(v.w);
    }
    float* o = u + (size_t)r * 64 + q * 8;
    *(float4*)o       = make_float4(a[0], a[1], a[2], a[3]);
    *(float4*)(o + 4) = make_float4(a[4], a[5], a[6], a[7]);
}

// Compute scale/shift from stats, then zero stats for the next layer.
__global__ void bn_finalize(
    float* __restrict__ stats, const float* __restrict__ gamma,
    const float* __restrict__ beta, float* __restrict__ sc, int layer)
{
    const int c = threadIdx.x; // 64 threads, 1 block
    const float mean = stats[c] * (1.0f / Nn);
    const float var = stats[64 + c] * (1.0f / Nn) - mean * mean;
    const float scale = gamma[layer * 64 + c] * rsqrtf(var + 1e-5f);
    sc[c] = scale;
    sc[64 + c] = beta[layer * 64 + c] - mean * scale;
    stats[c] = 0.f;
    stats[64 + c] = 0.f;
}

// ---------------------------------------------------------------------------
// Apply BN: read z (f32), write ONLY fp16 shadow h + per-graph pooled sums.
// 8 blocks per graph; batch is sorted.
// ---------------------------------------------------------------------------
__global__ __launch_bounds__(256) void bn_apply_pool(
    const float* __restrict__ z, ushort* __restrict__ hs,
    const int* __restrict__ batch, const float* __restrict__ sc,
    float* __restrict__ pooled, int layer)
{
    const int g = blockIdx.x >> 3;
    const int sub = blockIdx.x & 7;
    const int lo = lower_bound_i(batch, Nn, g);
    const int hi = lower_bound_i(batch, Nn, g + 1);
    const int t = threadIdx.x;
    const int cq = t & 15;                 // cols cq*4 .. +3
    const int rg = (t >> 4) + sub * 16;    // 0..127
    float scl[4], sft[4], acc[4] = {};
    #pragma unroll
    for (int i = 0; i < 4; i++) {
        scl[i] = sc[cq * 4 + i];
        sft[i] = sc[64 + cq * 4 + i];
    }
    for (int row = lo + rg; row < hi; row += 128) {
        const float4 v = *(const float4*)(z + (size_t)row * 64 + cq * 4);
        const float a0 = fmaf(scl[0], v.x, sft[0]);
        const float a1 = fmaf(scl[1], v.y, sft[1]);
        const float a2 = fmaf(scl[2], v.z, sft[2]);
        const float a3 = fmaf(scl[3], v.w, sft[3]);
        uint2 p;
        p.x = pack2h(a0, a1);
        p.y = pack2h(a2, a3);
        *(uint2*)(hs + (size_t)row * 64 + cq * 4) = p;
        acc[0] += a0; acc[1] += a1; acc[2] += a2; acc[3] += a3;
    }
    __shared__ float red[16][16][4];
    #pragma unroll
    for (int i = 0; i < 4; i++) red[t >> 4][cq][i] = acc[i];
    __syncthreads();
    if (t < 64) {
        const int c2 = t >> 2, j = t & 3;
        float s = 0.f;
        #pragma unroll
        for (int r = 0; r < 16; r++) s += red[r][c2][j];
        atomicAdd(&pooled[g * PDim + layer * 64 + c2 * 4 + j], s);
    }
}

// ---------------------------------------------------------------------------
// Proj head GEMM: (128,320)@(320,320)+b (f32, small).
// ---------------------------------------------------------------------------
template<bool RELU>
__global__ __launch_bounds__(256) void proj(
    const float* __restrict__ X, const float* __restrict__ W,
    const float* __restrict__ bias, float* __restrict__ Y)
{
    const int idx = blockIdx.x * 256 + threadIdx.x; // 40960 exact
    const int r = idx / PDim;
    const int c = idx - r * PDim;
    float acc = bias[c];
    #pragma unroll 8
    for (int k = 0; k < PDim; k++)
        acc = fmaf(X[r * PDim + k], W[k * PDim + c], acc);
    if constexpr (RELU) acc = fmaxf(acc, 0.f);
    Y[idx] = acc;
}

// ---------------------------------------------------------------------------
// Row-wise l2 normalize.
// ---------------------------------------------------------------------------
__global__ __launch_bounds__(64) void l2norm_rows(
    const float* __restrict__ X, float* __restrict__ out)
{
    const int r = blockIdx.x;
    const int l = threadIdx.x;
    float v[5];
    float s = 0.f;
    #pragma unroll
    for (int i = 0; i < 5; i++) {
        v[i] = X[r * PDim + i * 64 + l];
        s += v[i] * v[i];
    }
    #pragma unroll
    for (int off = 32; off > 0; off >>= 1) s += __shfl_down(s, off);
    s = __shfl(s, 0);
    const float d = fmaxf(sqrtf(s), 1e-12f);
    #pragma unroll
    for (int i = 0; i < 5; i++)
        out[r * PDim + i * 64 + l] = v[i] / d;
}

// ---------------------------------------------------------------------------
extern "C" void kernel_launch(void* const* d_in, const int* in_sizes, int n_in,
                              void* d_out, int out_size, void* d_ws, size_t ws_size,
                              hipStream_t stream)
{
    const float* x     = (const float*)d_in[0];
    const int*   ei    = (const int*)d_in[1];
    const int*   batch = (const int*)d_in[2];
    const float* Ws    = (const float*)d_in[3];
    const float* bs    = (const float*)d_in[4];
    const float* W1    = (const float*)d_in[5];
    const float* b1    = (const float*)d_in[6];
    const float* W2    = (const float*)d_in[7];
    const float* b2    = (const float*)d_in[8];
    const float* gamma = (const float*)d_in[9];
    const float* beta  = (const float*)d_in[10];
    const float* Wp1   = (const float*)d_in[11];
    const float* bp1   = (const float*)d_in[12];
    const float* Wp2   = (const float*)d_in[13];
    const float* bp2   = (const float*)d_in[14];
    float* out = (float*)d_out;

    // workspace (big 16B-aligned arrays first)
    float*  Uf  = (float*)d_ws;                   // u = self+agg (f32) 25.6MB
    float*  Zf  = Uf + (size_t)Nn * 64;           // z  f32            25.6MB
    ushort* Hs  = (ushort*)(Zf + (size_t)Nn * 64);// h fp16 shadow     12.8MB
    ushort* WThi = Hs + (size_t)Nn * 64;          // 11*4096 bf16
    ushort* WTlo = WThi + 11 * 4096;
    float* pooled = (float*)(WTlo + 11 * 4096);   // (G,320)
    float* ytmp   = pooled + (size_t)Gg * PDim;
    float* ypro   = ytmp + (size_t)Gg * PDim;
    float* stats  = ypro + (size_t)Gg * PDim;     // 128
    float* sc     = stats + 128;                  // 128
    int* rowptr = (int*)(sc + 128);               // Nn+1
    int* colidx = rowptr + Nn + 1;                // Ee
    int* gCursor = colidx + Ee;                   // 128 (NB used)
    int* bucketBase = gCursor + 128;              // 128
    size_t woff = (size_t)((bucketBase + 128) - (int*)d_ws);
    woff = (woff + 1) & ~(size_t)1;
    uint2* binned = (uint2*)((int*)d_ws + woff);  // NB*BCAP*8B = 12.6MB

    const int gemmGrid = (Nn + 63) / 64;          // 1563

    hipMemsetAsync(stats, 0, 128 * sizeof(float), stream);
    hipMemsetAsync(pooled, 0, (size_t)Gg * PDim * sizeof(float), stream);

    conv_weights<<<11, 256, 0, stream>>>(Ws, W1, W2, WThi, WTlo);

    // bucketed CSR build
    init_csr<<<1, 128, 0, stream>>>(gCursor);
    bin_edges<<<NBLK_A, 256, 0, stream>>>(ei, gCursor, binned);
    scan_buckets<<<1, 128, 0, stream>>>(gCursor, bucketBase);
    build_csr<<<NB, 256, 0, stream>>>(binned, gCursor, bucketBase, rowptr, colidx);

    // encoder: Hs = fp16(x @ Ws + bs)
    gemm_enc<<<gemmGrid, 256, 0, stream>>>(x, WThi, WTlo, bs, Hs);

    for (int l = 0; l < Ll; l++) {
        gather_agg_inc<<<Nn / 32, 256, 0, stream>>>(rowptr, colidx, Hs, Uf);
        fused_mlp<<<gemmGrid, 256, 0, stream>>>(
            Uf,
            WThi + (size_t)(1 + l) * 4096, WTlo + (size_t)(1 + l) * 4096,
            b1 + (size_t)l * 64,
            WThi + (size_t)(6 + l) * 4096, WTlo + (size_t)(6 + l) * 4096,
            b2 + (size_t)l * 64,
            Zf, stats);
        bn_finalize<<<1, 64, 0, stream>>>(stats, gamma, beta, sc, l);
        bn_apply_pool<<<Gg * 8, 256, 0, stream>>>(Zf, Hs, batch, sc, pooled, l);
    }

    // proj head (f32)
    proj<true><<<160, 256, 0, stream>>>(pooled, Wp1, bp1, ytmp);
    proj<false><<<160, 256, 0, stream>>>(ytmp, Wp2, bp2, ypro);

    l2norm_rows<<<Gg, 64, 0, stream>>>(ypro, out);               // out0
    l2norm_rows<<<Gg, 64, 0, stream>>>(pooled, out + Gg * PDim); // out1
}

// Round 12
// 641.985 us; speedup vs baseline: 1.5337x; 1.0409x over previous
//
#include <hip/hip_runtime.h>
#include <hip/hip_bf16.h>
#include <hip/hip_fp16.h>

constexpr int Nn = 100000;
constexpr int Ee = 1200000;
constexpr int Ll = 5;
constexpr int Gg = 128;
constexpr int PDim = 320; // L*D

// bucketed CSR build params
constexpr int NB    = 98;     // buckets of 1024 rows (dst >> 10)
constexpr int BCAP  = 16384;  // per-bucket edge capacity
constexpr int CHUNK = 4096;   // edges per bin_edges block
constexpr int NBLK_A = (Ee + CHUNK - 1) / CHUNK; // 293

typedef short short8 __attribute__((ext_vector_type(8)));
typedef float f32x4 __attribute__((ext_vector_type(4)));

union U4S8 { uint4 u; short8 s; };

__device__ inline ushort f2bf(float f) {
    const uint u = __float_as_uint(f);
    return (ushort)((u + 0x7fffu + ((u >> 16) & 1u)) >> 16);
}
__device__ inline uint pack2(float lo, float hi) {
    return (uint)f2bf(lo) | ((uint)f2bf(hi) << 16);
}
__device__ inline ushort f2h(float f) {
    const __half h = __float2half(f);
    return *(const ushort*)&h;
}
__device__ inline uint pack2h(float lo, float hi) {
    return (uint)f2h(lo) | ((uint)f2h(hi) << 16);
}
__device__ inline float h2f_lo(uint u) {
    const ushort s = (ushort)(u & 0xffffu);
    return __half2float(*(const __half*)&s);
}
__device__ inline float h2f_hi(uint u) {
    const ushort s = (ushort)(u >> 16);
    return __half2float(*(const __half*)&s);
}
// split x0,x1 into packed bf16 hi word + bf16 lo (residual) word
__device__ inline void split2(float x0, float x1, uint& hi, uint& lo) {
    const ushort h0 = f2bf(x0), h1 = f2bf(x1);
    hi = (uint)h0 | ((uint)h1 << 16);
    const float r0 = x0 - __uint_as_float((uint)h0 << 16);
    const float r1 = x1 - __uint_as_float((uint)h1 << 16);
    lo = pack2(r0, r1);
}

__device__ inline int lower_bound_i(const int* __restrict__ a, int n, int v)
{
    int lo = 0, hi = n;
    while (lo < hi) {
        const int m = (lo + hi) >> 1;
        if (a[m] < v) lo = m + 1; else hi = m;
    }
    return lo;
}

// ---------------------------------------------------------------------------
// init: gCursor for buckets, per-graph node counts, identity BN sc.
// ---------------------------------------------------------------------------
__global__ void init_csr(const int* __restrict__ batch, int* __restrict__ gCursor,
                         int* __restrict__ cnt, float* __restrict__ sc)
{
    const int t = threadIdx.x; // 128
    if (t < NB) gCursor[t] = t * BCAP;
    {
        const int lo = lower_bound_i(batch, Nn, t);
        const int hi = lower_bound_i(batch, Nn, t + 1);
        cnt[t] = hi - lo;
    }
    if (t < 64) { sc[t] = 1.f; sc[64 + t] = 0.f; }
}

// ---------------------------------------------------------------------------
// Weight conversion: 11 64x64 f32 matrices -> TRANSPOSED bf16 hi/lo pair.
// Block m: 0=Ws, 1..5=W1[m-1], 6..10=W2[m-6].
// ---------------------------------------------------------------------------
__global__ __launch_bounds__(256) void conv_weights(
    const float* __restrict__ Ws, const float* __restrict__ W1,
    const float* __restrict__ W2, ushort* __restrict__ WThi,
    ushort* __restrict__ WTlo)
{
    const int m = blockIdx.x;
    const float* src = (m == 0) ? Ws
                     : (m <= 5) ? W1 + (size_t)(m - 1) * 4096
                                : W2 + (size_t)(m - 6) * 4096;
    ushort* dh = WThi + (size_t)m * 4096;
    ushort* dl = WTlo + (size_t)m * 4096;
    const int t = threadIdx.x;
    const int col = t & 63;
    const int k0 = (t >> 6) * 16;
    #pragma unroll
    for (int i = 0; i < 16; i++) {
        const int k = k0 + i;
        const float w = src[k * 64 + col];
        const ushort h = f2bf(w);
        dh[col * 64 + k] = h;
        dl[col * 64 + k] = f2bf(w - __uint_as_float((uint)h << 16));
    }
}

// ---------------------------------------------------------------------------
// Encoder GEMM: Zs = fp16(x @ Ws + bs). Split-bf16 MFMA.
// ---------------------------------------------------------------------------
__global__ __launch_bounds__(256) void gemm_enc(
    const float* __restrict__ A1,
    const ushort* __restrict__ WThi, const ushort* __restrict__ WTlo,
    const float* __restrict__ bias, ushort* __restrict__ Ys)
{
    const int t = threadIdx.x;
    const int w = t >> 6;
    const int l = t & 63;
    const int lr = l & 15;
    const int lk = l >> 4;

    short8 bHi[4][2], bLo[4][2];
    #pragma unroll
    for (int nt = 0; nt < 4; nt++)
        #pragma unroll
        for (int c = 0; c < 2; c++) {
            const int off = (nt * 16 + lr) * 64 + c * 32 + lk * 8;
            U4S8 uh, ul;
            uh.u = *(const uint4*)(WThi + off);
            ul.u = *(const uint4*)(WTlo + off);
            bHi[nt][c] = uh.s;
            bLo[nt][c] = ul.s;
        }

    const int arow = blockIdx.x * 64 + w * 16 + lr;
    short8 aHi[2], aLo[2];
    if (arow < Nn) {
        #pragma unroll
        for (int c = 0; c < 2; c++) {
            const float* p1 = A1 + (size_t)arow * 64 + c * 32 + lk * 8;
            const float4 v0 = *(const float4*)p1;
            const float4 v1 = *(const float4*)(p1 + 4);
            U4S8 rh, rl;
            uint* ph = (uint*)&rh.u;
            uint* pl = (uint*)&rl.u;
            split2(v0.x, v0.y, ph[0], pl[0]);
            split2(v0.z, v0.w, ph[1], pl[1]);
            split2(v1.x, v1.y, ph[2], pl[2]);
            split2(v1.z, v1.w, ph[3], pl[3]);
            aHi[c] = rh.s;
            aLo[c] = rl.s;
        }
    } else {
        U4S8 z; z.u = make_uint4(0, 0, 0, 0);
        aHi[0] = aHi[1] = z.s;
        aLo[0] = aLo[1] = z.s;
    }

    f32x4 acc[4] = {};
    #pragma unroll
    for (int nt = 0; nt < 4; nt++)
        #pragma unroll
        for (int c = 0; c < 2; c++) {
            acc[nt] = __builtin_amdgcn_mfma_f32_16x16x32_bf16(
                aLo[c], bHi[nt][c], acc[nt], 0, 0, 0);
            acc[nt] = __builtin_amdgcn_mfma_f32_16x16x32_bf16(
                aHi[c], bLo[nt][c], acc[nt], 0, 0, 0);
            acc[nt] = __builtin_amdgcn_mfma_f32_16x16x32_bf16(
                aHi[c], bHi[nt][c], acc[nt], 0, 0, 0);
        }

    #pragma unroll
    for (int nt = 0; nt < 4; nt++) {
        const int ccol = nt * 16 + lr;
        const float bb = bias[ccol];
        #pragma unroll
        for (int j = 0; j < 4; j++) {
            const int crow = blockIdx.x * 64 + w * 16 + lk * 4 + j;
            if (crow < Nn)
                Ys[(size_t)crow * 64 + ccol] = f2h(acc[nt][j] + bb);
        }
    }
}

// ---------------------------------------------------------------------------
// Fused GIN MLP: Zs = fp16(relu(relu(u@W1+b1)@W2+b2)), u fp16 in,
// fused per-column BN stats (f32, pre-rounding). M in LDS as fp16 [64][72].
// ---------------------------------------------------------------------------
__global__ __launch_bounds__(256) void fused_mlp(
    const ushort* __restrict__ Us,
    const ushort* __restrict__ WT1hi, const ushort* __restrict__ WT1lo,
    const float* __restrict__ b1v,
    const ushort* __restrict__ WT2hi, const ushort* __restrict__ WT2lo,
    const float* __restrict__ b2v,
    ushort* __restrict__ Zs, float* __restrict__ stats)
{
    const int t = threadIdx.x;
    const int w = t >> 6;
    const int l = t & 63;
    const int lr = l & 15;   // A-row / B-col within 16-tile
    const int lk = l >> 4;   // k-group (8 elems each)

    __shared__ ushort Mh[64][72];
    __shared__ float red[2][4][4][16];

    // ---- stage 1: M = relu(u @ W1 + b1) ----
    short8 b1Hi[4][2], b1Lo[4][2];
    #pragma unroll
    for (int nt = 0; nt < 4; nt++)
        #pragma unroll
        for (int c = 0; c < 2; c++) {
            const int off = (nt * 16 + lr) * 64 + c * 32 + lk * 8;
            U4S8 uh, ul;
            uh.u = *(const uint4*)(WT1hi + off);
            ul.u = *(const uint4*)(WT1lo + off);
            b1Hi[nt][c] = uh.s;
            b1Lo[nt][c] = ul.s;
        }

    const int arow = blockIdx.x * 64 + w * 16 + lr;
    short8 aHi[2], aLo[2];
    if (arow < Nn) {
        #pragma unroll
        for (int c = 0; c < 2; c++) {
            const uint4 v = *(const uint4*)(Us + (size_t)arow * 64 + c * 32 + lk * 8);
            U4S8 rh, rl;
            uint* ph = (uint*)&rh.u;
            uint* pl = (uint*)&rl.u;
            split2(h2f_lo(v.x), h2f_hi(v.x), ph[0], pl[0]);
            split2(h2f_lo(v.y), h2f_hi(v.y), ph[1], pl[1]);
            split2(h2f_lo(v.z), h2f_hi(v.z), ph[2], pl[2]);
            split2(h2f_lo(v.w), h2f_hi(v.w), ph[3], pl[3]);
            aHi[c] = rh.s;
            aLo[c] = rl.s;
        }
    } else {
        U4S8 z; z.u = make_uint4(0, 0, 0, 0);
        aHi[0] = aHi[1] = z.s;
        aLo[0] = aLo[1] = z.s;
    }

    f32x4 acc[4] = {};
    #pragma unroll
    for (int nt = 0; nt < 4; nt++)
        #pragma unroll
        for (int c = 0; c < 2; c++) {
            acc[nt] = __builtin_amdgcn_mfma_f32_16x16x32_bf16(
                aLo[c], b1Hi[nt][c], acc[nt], 0, 0, 0);
            acc[nt] = __builtin_amdgcn_mfma_f32_16x16x32_bf16(
                aHi[c], b1Lo[nt][c], acc[nt], 0, 0, 0);
            acc[nt] = __builtin_amdgcn_mfma_f32_16x16x32_bf16(
                aHi[c], b1Hi[nt][c], acc[nt], 0, 0, 0);
        }

    // M -> LDS (fp16); C/D layout: row = lk*4+j, col = nt*16+lr [m89]
    #pragma unroll
    for (int nt = 0; nt < 4; nt++) {
        const int ccol = nt * 16 + lr;
        const float bb = b1v[ccol];
        #pragma unroll
        for (int j = 0; j < 4; j++) {
            const int rloc = w * 16 + lk * 4 + j;
            Mh[rloc][ccol] = f2h(fmaxf(acc[nt][j] + bb, 0.f));
        }
    }
    __syncthreads();

    // ---- stage 2: z = relu(M @ W2 + b2) ----
    short8 b2Hi[4][2], b2Lo[4][2];
    #pragma unroll
    for (int nt = 0; nt < 4; nt++)
        #pragma unroll
        for (int c = 0; c < 2; c++) {
            const int off = (nt * 16 + lr) * 64 + c * 32 + lk * 8;
            U4S8 uh, ul;
            uh.u = *(const uint4*)(WT2hi + off);
            ul.u = *(const uint4*)(WT2lo + off);
            b2Hi[nt][c] = uh.s;
            b2Lo[nt][c] = ul.s;
        }

    short8 a2Hi[2], a2Lo[2];
    #pragma unroll
    for (int c = 0; c < 2; c++) {
        const uint4 v = *(const uint4*)&Mh[w * 16 + lr][c * 32 + lk * 8];
        U4S8 rh, rl;
        uint* ph = (uint*)&rh.u;
        uint* pl = (uint*)&rl.u;
        split2(h2f_lo(v.x), h2f_hi(v.x), ph[0], pl[0]);
        split2(h2f_lo(v.y), h2f_hi(v.y), ph[1], pl[1]);
        split2(h2f_lo(v.z), h2f_hi(v.z), ph[2], pl[2]);
        split2(h2f_lo(v.w), h2f_hi(v.w), ph[3], pl[3]);
        a2Hi[c] = rh.s;
        a2Lo[c] = rl.s;
    }

    f32x4 acc2[4] = {};
    #pragma unroll
    for (int nt = 0; nt < 4; nt++)
        #pragma unroll
        for (int c = 0; c < 2; c++) {
            acc2[nt] = __builtin_amdgcn_mfma_f32_16x16x32_bf16(
                a2Lo[c], b2Hi[nt][c], acc2[nt], 0, 0, 0);
            acc2[nt] = __builtin_amdgcn_mfma_f32_16x16x32_bf16(
                a2Hi[c], b2Lo[nt][c], acc2[nt], 0, 0, 0);
            acc2[nt] = __builtin_amdgcn_mfma_f32_16x16x32_bf16(
                a2Hi[c], b2Hi[nt][c], acc2[nt], 0, 0, 0);
        }

    float s[4], s2[4];
    #pragma unroll
    for (int nt = 0; nt < 4; nt++) {
        const int ccol = nt * 16 + lr;
        const float bb = b2v[ccol];
        s[nt] = 0.f; s2[nt] = 0.f;
        #pragma unroll
        for (int j = 0; j < 4; j++) {
            const int crow = blockIdx.x * 64 + w * 16 + lk * 4 + j;
            if (crow < Nn) {
                const float v = fmaxf(acc2[nt][j] + bb, 0.f);
                Zs[(size_t)crow * 64 + ccol] = f2h(v);
                s[nt] += v; s2[nt] += v * v;
            }
        }
    }

    #pragma unroll
    for (int nt = 0; nt < 4; nt++) {
        s[nt]  += __shfl_xor(s[nt], 16);  s[nt]  += __shfl_xor(s[nt], 32);
        s2[nt] += __shfl_xor(s2[nt], 16); s2[nt] += __shfl_xor(s2[nt], 32);
    }
    if (l < 16) {
        #pragma unroll
        for (int nt = 0; nt < 4; nt++) {
            red[0][w][nt][l] = s[nt];
            red[1][w][nt][l] = s2[nt];
        }
    }
    __syncthreads();
    if (t < 64) { // column = (t>>4)*16 + (t&15) = t
        float ts = 0.f, ts2 = 0.f;
        #pragma unroll
        for (int wv = 0; wv < 4; wv++) {
            ts  += red[0][wv][t >> 4][t & 15];
            ts2 += red[1][wv][t >> 4][t & 15];
        }
        atomicAdd(&stats[t], ts);
        atomicAdd(&stats[64 + t], ts2);
    }
}

// ---------------------------------------------------------------------------
// Bucketed CSR build.
// ---------------------------------------------------------------------------
__global__ __launch_bounds__(256) void bin_edges(
    const int* __restrict__ ei, int* __restrict__ gCursor,
    uint2* __restrict__ binned)
{
    __shared__ int hist[NB];
    __shared__ int base[NB];
    __shared__ int cur[NB];
    const int t = threadIdx.x;
    const int e0 = blockIdx.x * CHUNK;
    const int eEnd = min(e0 + CHUNK, Ee);
    if (t < NB) hist[t] = 0;
    __syncthreads();
    for (int e = e0 + t; e < eEnd; e += 256)
        atomicAdd(&hist[ei[Ee + e] >> 10], 1);
    __syncthreads();
    if (t < NB) {
        base[t] = atomicAdd(&gCursor[t], hist[t]);
        cur[t] = 0;
    }
    __syncthreads();
    for (int e = e0 + t; e < eEnd; e += 256) {
        const int s = ei[e];
        const int d = ei[Ee + e];
        const int b = d >> 10;
        const int pos = atomicAdd(&cur[b], 1);
        binned[(size_t)base[b] + pos] = make_uint2((uint)d, (uint)s);
    }
}

__global__ __launch_bounds__(128) void scan_buckets(
    const int* __restrict__ gCursor, int* __restrict__ bucketBase)
{
    __shared__ int sh[128];
    const int t = threadIdx.x;
    const int c = (t < NB) ? gCursor[t] - t * BCAP : 0;
    sh[t] = c;
    __syncthreads();
    for (int off = 1; off < 128; off <<= 1) {
        const int u = (t >= off) ? sh[t - off] : 0;
        __syncthreads();
        sh[t] += u;
        __syncthreads();
    }
    bucketBase[t] = sh[t] - c; // exclusive
}

__global__ __launch_bounds__(256) void build_csr(
    const uint2* __restrict__ binned, const int* __restrict__ gCursor,
    const int* __restrict__ bucketBase, int* __restrict__ rowptr,
    int* __restrict__ colidx)
{
    __shared__ int degS[1024];
    __shared__ int sh[256];
    __shared__ int colStage[BCAP];
    const int b = blockIdx.x;
    const int t = threadIdx.x;
    const int cnt = gCursor[b] - b * BCAP;
    const int base = bucketBase[b];
    const uint2* src = binned + (size_t)b * BCAP;

    for (int i = t; i < 1024; i += 256) degS[i] = 0;
    __syncthreads();
    for (int i = t; i < cnt; i += 256)
        atomicAdd(&degS[src[i].x & 1023], 1);
    __syncthreads();

    const int b4 = t * 4;
    const int v0 = degS[b4], v1 = degS[b4 + 1], v2 = degS[b4 + 2], v3 = degS[b4 + 3];
    const int sSum = v0 + v1 + v2 + v3;
    sh[t] = sSum;
    __syncthreads();
    for (int off = 1; off < 256; off <<= 1) {
        const int u = (t >= off) ? sh[t - off] : 0;
        __syncthreads();
        sh[t] += u;
        __syncthreads();
    }
    const int excl = sh[t] - sSum;
    const int p0 = excl, p1 = excl + v0, p2 = excl + v0 + v1, p3 = excl + v0 + v1 + v2;

    const int grow = b * 1024 + b4;
    if (grow + 3 <= Nn) {
        *(int4*)(rowptr + grow) = make_int4(base + p0, base + p1, base + p2, base + p3);
    } else {
        if (grow + 0 <= Nn) rowptr[grow + 0] = base + p0;
        if (grow + 1 <= Nn) rowptr[grow + 1] = base + p1;
        if (grow + 2 <= Nn) rowptr[grow + 2] = base + p2;
        if (grow + 3 <= Nn) rowptr[grow + 3] = base + p3;
    }

    degS[b4] = p0; degS[b4 + 1] = p1; degS[b4 + 2] = p2; degS[b4 + 3] = p3;
    __syncthreads();
    for (int i = t; i < cnt; i += 256) {
        const uint2 p = src[i];
        const int pos = atomicAdd(&degS[p.x & 1023], 1);
        colStage[pos] = (int)p.y;
    }
    __syncthreads();
    for (int i = t; i < cnt; i += 256) colidx[base + i] = colStage[i];
}

// ---------------------------------------------------------------------------
// Gather + deferred BN: u[r] = scale ∘ (z[r] + Σ_{j∈N(r)} z[j]) + (1+deg)*shift,
// z fp16 in, u fp16 out, affine in f32. 8 lanes per row, 32 rows per block.
// ---------------------------------------------------------------------------
__global__ __launch_bounds__(256) void gather_bn(
    const int* __restrict__ rowptr, const int* __restrict__ col,
    const ushort* __restrict__ zs, const float* __restrict__ sc,
    ushort* __restrict__ us)
{
    __shared__ float scS[128];
    const int t = threadIdx.x;
    if (t < 128) scS[t] = sc[t];
    __syncthreads();

    const int r = blockIdx.x * 32 + (t >> 3);
    const int q = t & 7;
    const int beg = rowptr[r], end = rowptr[r + 1];
    float a[8];
    {
        const uint4 v = *(const uint4*)(zs + (size_t)r * 64 + q * 8); // self
        a[0] = h2f_lo(v.x); a[1] = h2f_hi(v.x);
        a[2] = h2f_lo(v.y); a[3] = h2f_hi(v.y);
        a[4] = h2f_lo(v.z); a[5] = h2f_hi(v.z);
        a[6] = h2f_lo(v.w); a[7] = h2f_hi(v.w);
    }
    for (int j = beg; j < end; j++) {
        const int s = col[j];
        const uint4 v = *(const uint4*)(zs + (size_t)s * 64 + q * 8);
        a[0] += h2f_lo(v.x); a[1] += h2f_hi(v.x);
        a[2] += h2f_lo(v.y); a[3] += h2f_hi(v.y);
        a[4] += h2f_lo(v.z); a[5] += h2f_hi(v.z);
        a[6] += h2f_lo(v.w); a[7] += h2f_hi(v.w);
    }
    const float dgf = (float)(end - beg + 1);
    float o[8];
    #pragma unroll
    for (int i = 0; i < 8; i++)
        o[i] = fmaf(scS[q * 8 + i], a[i], dgf * scS[64 + q * 8 + i]);
    uint4 p;
    p.x = pack2h(o[0], o[1]); p.y = pack2h(o[2], o[3]);
    p.z = pack2h(o[4], o[5]); p.w = pack2h(o[6], o[7]);
    *(uint4*)(us + (size_t)r * 64 + q * 8) = p;
}

// Compute scale/shift from stats -> sc (current) + sc5[layer]; zero stats.
__global__ void bn_finalize(
    float* __restrict__ stats, const float* __restrict__ gamma,
    const float* __restrict__ beta, float* __restrict__ sc,
    float* __restrict__ sc5, int layer)
{
    const int c = threadIdx.x; // 64 threads, 1 block
    const float mean = stats[c] * (1.0f / Nn);
    const float var = stats[64 + c] * (1.0f / Nn) - mean * mean;
    const float scale = gamma[layer * 64 + c] * rsqrtf(var + 1e-5f);
    const float shift = beta[layer * 64 + c] - mean * scale;
    sc[c] = scale;
    sc[64 + c] = shift;
    sc5[layer * 128 + c] = scale;
    sc5[layer * 128 + 64 + c] = shift;
    stats[c] = 0.f;
    stats[64 + c] = 0.f;
}

// ---------------------------------------------------------------------------
// Per-graph raw-z column sums (fp16 in, f32 accum). 8 blocks/graph.
// ---------------------------------------------------------------------------
__global__ __launch_bounds__(256) void pool_z(
    const ushort* __restrict__ zs, const int* __restrict__ batch,
    float* __restrict__ poolZ)
{
    const int g = blockIdx.x >> 3;
    const int sub = blockIdx.x & 7;
    const int lo = lower_bound_i(batch, Nn, g);
    const int hi = lower_bound_i(batch, Nn, g + 1);
    const int t = threadIdx.x;
    const int cq = t & 15;                 // cols cq*4 .. +3
    const int rg = (t >> 4) + sub * 16;    // 0..127
    float acc[4] = {};
    for (int row = lo + rg; row < hi; row += 128) {
        const uint2 p = *(const uint2*)(zs + (size_t)row * 64 + cq * 4);
        acc[0] += h2f_lo(p.x); acc[1] += h2f_hi(p.x);
        acc[2] += h2f_lo(p.y); acc[3] += h2f_hi(p.y);
    }
    __shared__ float red[16][16][4];
    #pragma unroll
    for (int i = 0; i < 4; i++) red[t >> 4][cq][i] = acc[i];
    __syncthreads();
    if (t < 64) {
        const int c2 = t >> 2, j = t & 3;
        float s = 0.f;
        #pragma unroll
        for (int r = 0; r < 16; r++) s += red[r][c2][j];
        atomicAdd(&poolZ[g * 64 + c2 * 4 + j], s);
    }
}

// ---------------------------------------------------------------------------
// Final pooled transform across all layers:
// pooled[g][l*64+c] = sc5[l][c]*poolZ[l][g][c] + cnt[g]*sc5[l][64+c]
// ---------------------------------------------------------------------------
__global__ __launch_bounds__(256) void final_pool(
    const float* __restrict__ sc5, const float* __restrict__ poolZ,
    const int* __restrict__ cnt, float* __restrict__ pooled)
{
    const int idx = blockIdx.x * 256 + threadIdx.x; // 40960
    const int c = idx & 63;
    const int g = (idx >> 6) & 127;
    const int l = idx >> 13;
    pooled[g * PDim + l * 64 + c] =
        sc5[l * 128 + c] * poolZ[(size_t)l * Gg * 64 + g * 64 + c]
        + (float)cnt[g] * sc5[l * 128 + 64 + c];
}

// ---------------------------------------------------------------------------
// Proj head GEMM: (128,320)@(320,320)+b (f32, small).
// ---------------------------------------------------------------------------
template<bool RELU>
__global__ __launch_bounds__(256) void proj(
    const float* __restrict__ X, const float* __restrict__ W,
    const float* __restrict__ bias, float* __restrict__ Y)
{
    const int idx = blockIdx.x * 256 + threadIdx.x; // 40960 exact
    const int r = idx / PDim;
    const int c = idx - r * PDim;
    float acc = bias[c];
    #pragma unroll 8
    for (int k = 0; k < PDim; k++)
        acc = fmaf(X[r * PDim + k], W[k * PDim + c], acc);
    if constexpr (RELU) acc = fmaxf(acc, 0.f);
    Y[idx] = acc;
}

// ---------------------------------------------------------------------------
// Row-wise l2 normalize.
// ---------------------------------------------------------------------------
__global__ __launch_bounds__(64) void l2norm_rows(
    const float* __restrict__ X, float* __restrict__ out)
{
    const int r = blockIdx.x;
    const int l = threadIdx.x;
    float v[5];
    float s = 0.f;
    #pragma unroll
    for (int i = 0; i < 5; i++) {
        v[i] = X[r * PDim + i * 64 + l];
        s += v[i] * v[i];
    }
    #pragma unroll
    for (int off = 32; off > 0; off >>= 1) s += __shfl_down(s, off);
    s = __shfl(s, 0);
    const float d = fmaxf(sqrtf(s), 1e-12f);
    #pragma unroll
    for (int i = 0; i < 5; i++)
        out[r * PDim + i * 64 + l] = v[i] / d;
}

// ---------------------------------------------------------------------------
extern "C" void kernel_launch(void* const* d_in, const int* in_sizes, int n_in,
                              void* d_out, int out_size, void* d_ws, size_t ws_size,
                              hipStream_t stream)
{
    const float* x     = (const float*)d_in[0];
    const int*   ei    = (const int*)d_in[1];
    const int*   batch = (const int*)d_in[2];
    const float* Ws    = (const float*)d_in[3];
    const float* bs    = (const float*)d_in[4];
    const float* W1    = (const float*)d_in[5];
    const float* b1    = (const float*)d_in[6];
    const float* W2    = (const float*)d_in[7];
    const float* b2    = (const float*)d_in[8];
    const float* gamma = (const float*)d_in[9];
    const float* beta  = (const float*)d_in[10];
    const float* Wp1   = (const float*)d_in[11];
    const float* bp1   = (const float*)d_in[12];
    const float* Wp2   = (const float*)d_in[13];
    const float* bp2   = (const float*)d_in[14];
    float* out = (float*)d_out;

    // workspace
    ushort* Us = (ushort*)d_ws;                   // u  fp16 (N*64)  12.8MB
    ushort* Zs = Us + (size_t)Nn * 64;            // z  fp16         12.8MB
    ushort* WThi = Zs + (size_t)Nn * 64;          // 11*4096 bf16
    ushort* WTlo = WThi + 11 * 4096;
    float* pooled = (float*)(WTlo + 11 * 4096);   // (G,320)
    float* ytmp   = pooled + (size_t)Gg * PDim;
    float* ypro   = ytmp + (size_t)Gg * PDim;
    float* stats  = ypro + (size_t)Gg * PDim;     // 128
    float* sc     = stats + 128;                  // 128
    float* sc5    = sc + 128;                     // 5*128
    float* poolZ  = sc5 + 5 * 128;                // 5*G*64
    int* cnt    = (int*)(poolZ + 5 * Gg * 64);    // 128
    int* rowptr = cnt + 128;                      // Nn+1
    int* colidx = rowptr + Nn + 1;                // Ee
    int* gCursor = colidx + Ee;                   // 128 (NB used)
    int* bucketBase = gCursor + 128;              // 128
    size_t woff = (size_t)((bucketBase + 128) - (int*)d_ws);
    woff = (woff + 1) & ~(size_t)1;
    uint2* binned = (uint2*)((int*)d_ws + woff);  // NB*BCAP*8B = 12.6MB

    const int gemmGrid = (Nn + 63) / 64;          // 1563

    hipMemsetAsync(stats, 0, 128 * sizeof(float), stream);
    hipMemsetAsync(poolZ, 0, 5 * Gg * 64 * sizeof(float), stream);

    init_csr<<<1, 128, 0, stream>>>(batch, gCursor, cnt, sc);
    conv_weights<<<11, 256, 0, stream>>>(Ws, W1, W2, WThi, WTlo);

    // bucketed CSR build
    bin_edges<<<NBLK_A, 256, 0, stream>>>(ei, gCursor, binned);
    scan_buckets<<<1, 128, 0, stream>>>(gCursor, bucketBase);
    build_csr<<<NB, 256, 0, stream>>>(binned, gCursor, bucketBase, rowptr, colidx);

    // encoder: Zs = fp16(x @ Ws + bs)   (raw z_0; BN identity in sc)
    gemm_enc<<<gemmGrid, 256, 0, stream>>>(x, WThi, WTlo, bs, Zs);

    for (int l = 0; l < Ll; l++) {
        // u = BN_{l-1} applied to inclusive sum of raw z (affine distributes)
        gather_bn<<<Nn / 32, 256, 0, stream>>>(rowptr, colidx, Zs, sc, Us);
        fused_mlp<<<gemmGrid, 256, 0, stream>>>(
            Us,
            WThi + (size_t)(1 + l) * 4096, WTlo + (size_t)(1 + l) * 4096,
            b1 + (size_t)l * 64,
            WThi + (size_t)(6 + l) * 4096, WTlo + (size_t)(6 + l) * 4096,
            b2 + (size_t)l * 64,
            Zs, stats);
        bn_finalize<<<1, 64, 0, stream>>>(stats, gamma, beta, sc, sc5, l);
        pool_z<<<Gg * 8, 256, 0, stream>>>(Zs, batch, poolZ + (size_t)l * Gg * 64);
    }

    final_pool<<<160, 256, 0, stream>>>(sc5, poolZ, cnt, pooled);

    // proj head (f32)
    proj<true><<<160, 256, 0, stream>>>(pooled, Wp1, bp1, ytmp);
    proj<false><<<160, 256, 0, stream>>>(ytmp, Wp2, bp2, ypro);

    l2norm_rows<<<Gg, 64, 0, stream>>>(ypro, out);               // out0
    l2norm_rows<<<Gg, 64, 0, stream>>>(pooled, out + Gg * PDim); // out1
}

// Round 13
// 632.292 us; speedup vs baseline: 1.5572x; 1.0153x over previous
//
#include <hip/hip_runtime.h>
#include <hip/hip_bf16.h>
#include <hip/hip_fp16.h>

constexpr int Nn = 100000;
constexpr int Ee = 1200000;
constexpr int Ll = 5;
constexpr int Gg = 128;
constexpr int PDim = 320; // L*D

// bucketed CSR build params
constexpr int NB    = 98;     // buckets of 1024 rows (dst >> 10)
constexpr int BCAP  = 16384;  // per-bucket edge capacity
constexpr int CHUNK = 4096;   // edges per bin_edges block
constexpr int NBLK_A = (Ee + CHUNK - 1) / CHUNK; // 293

typedef float f32x4 __attribute__((ext_vector_type(4)));
typedef _Float16 half8 __attribute__((ext_vector_type(8)));

union U4H8 { uint4 u; half8 h; };

__device__ inline ushort f2h(float f) {
    const __half h = __float2half(f);
    return *(const ushort*)&h;
}
__device__ inline uint pack2h(float lo, float hi) {
    return (uint)f2h(lo) | ((uint)f2h(hi) << 16);
}
__device__ inline float h2f_lo(uint u) {
    const ushort s = (ushort)(u & 0xffffu);
    return __half2float(*(const __half*)&s);
}
__device__ inline float h2f_hi(uint u) {
    const ushort s = (ushort)(u >> 16);
    return __half2float(*(const __half*)&s);
}

__device__ inline int lower_bound_i(const int* __restrict__ a, int n, int v)
{
    int lo = 0, hi = n;
    while (lo < hi) {
        const int m = (lo + hi) >> 1;
        if (a[m] < v) lo = m + 1; else hi = m;
    }
    return lo;
}

// ---------------------------------------------------------------------------
// init: gCursor for buckets, per-graph node counts, identity BN sc.
// ---------------------------------------------------------------------------
__global__ void init_csr(const int* __restrict__ batch, int* __restrict__ gCursor,
                         int* __restrict__ cnt, float* __restrict__ sc)
{
    const int t = threadIdx.x; // 128
    if (t < NB) gCursor[t] = t * BCAP;
    {
        const int lo = lower_bound_i(batch, Nn, t);
        const int hi = lower_bound_i(batch, Nn, t + 1);
        cnt[t] = hi - lo;
    }
    if (t < 64) { sc[t] = 1.f; sc[64 + t] = 0.f; }
}

// ---------------------------------------------------------------------------
// Weight conversion: 11 64x64 f32 matrices -> TRANSPOSED fp16 hi + fp16
// (residual*2048) lo. 22-bit effective weight precision.
// Block m: 0=Ws, 1..5=W1[m-1], 6..10=W2[m-6].
// ---------------------------------------------------------------------------
__global__ __launch_bounds__(256) void conv_weights(
    const float* __restrict__ Ws, const float* __restrict__ W1,
    const float* __restrict__ W2, ushort* __restrict__ WThi,
    ushort* __restrict__ WTlo)
{
    const int m = blockIdx.x;
    const float* src = (m == 0) ? Ws
                     : (m <= 5) ? W1 + (size_t)(m - 1) * 4096
                                : W2 + (size_t)(m - 6) * 4096;
    ushort* dh = WThi + (size_t)m * 4096;
    ushort* dl = WTlo + (size_t)m * 4096;
    const int t = threadIdx.x;
    const int col = t & 63;
    const int k0 = (t >> 6) * 16;
    #pragma unroll
    for (int i = 0; i < 16; i++) {
        const int k = k0 + i;
        const float w = src[k * 64 + col];
        const ushort h = f2h(w);
        dh[col * 64 + k] = h;
        const float resid = (w - h2f_lo((uint)h)) * 2048.0f;
        dl[col * 64 + k] = f2h(resid);
    }
}

// ---------------------------------------------------------------------------
// Encoder GEMM (fp16 MFMA): Zs = fp16(x @ Ws + bs).
// x split into fp16 hi + fp16 lo*2048; acc = Ah@Wh + (Ah@Wl + Al@Wh)/2048.
// ---------------------------------------------------------------------------
__global__ __launch_bounds__(256) void gemm_enc(
    const float* __restrict__ A1,
    const ushort* __restrict__ WThi, const ushort* __restrict__ WTlo,
    const float* __restrict__ bias, ushort* __restrict__ Ys)
{
    const int t = threadIdx.x;
    const int w = t >> 6;
    const int l = t & 63;
    const int lr = l & 15;
    const int lk = l >> 4;

    half8 bHi[4][2], bLo[4][2];
    #pragma unroll
    for (int nt = 0; nt < 4; nt++)
        #pragma unroll
        for (int c = 0; c < 2; c++) {
            const int off = (nt * 16 + lr) * 64 + c * 32 + lk * 8;
            U4H8 uh, ul;
            uh.u = *(const uint4*)(WThi + off);
            ul.u = *(const uint4*)(WTlo + off);
            bHi[nt][c] = uh.h;
            bLo[nt][c] = ul.h;
        }

    const int arow = blockIdx.x * 64 + w * 16 + lr;
    half8 aHi[2], aLo[2];
    if (arow < Nn) {
        #pragma unroll
        for (int c = 0; c < 2; c++) {
            const float* p1 = A1 + (size_t)arow * 64 + c * 32 + lk * 8;
            U4H8 rh, rl;
            #pragma unroll
            for (int i = 0; i < 8; i++) {
                const float xv = p1[i];
                const _Float16 xh = (_Float16)xv;
                rh.h[i] = xh;
                rl.h[i] = (_Float16)((xv - (float)xh) * 2048.0f);
            }
            aHi[c] = rh.h;
            aLo[c] = rl.h;
        }
    } else {
        U4H8 z; z.u = make_uint4(0, 0, 0, 0);
        aHi[0] = aHi[1] = z.h;
        aLo[0] = aLo[1] = z.h;
    }

    f32x4 accH[4] = {}, accL[4] = {};
    #pragma unroll
    for (int nt = 0; nt < 4; nt++)
        #pragma unroll
        for (int c = 0; c < 2; c++) {
            accH[nt] = __builtin_amdgcn_mfma_f32_16x16x32_f16(
                aHi[c], bHi[nt][c], accH[nt], 0, 0, 0);
            accL[nt] = __builtin_amdgcn_mfma_f32_16x16x32_f16(
                aHi[c], bLo[nt][c], accL[nt], 0, 0, 0);
            accL[nt] = __builtin_amdgcn_mfma_f32_16x16x32_f16(
                aLo[c], bHi[nt][c], accL[nt], 0, 0, 0);
        }

    #pragma unroll
    for (int nt = 0; nt < 4; nt++) {
        const int ccol = nt * 16 + lr;
        const float bb = bias[ccol];
        #pragma unroll
        for (int j = 0; j < 4; j++) {
            const int crow = blockIdx.x * 64 + w * 16 + lk * 4 + j;
            if (crow < Nn)
                Ys[(size_t)crow * 64 + ccol] =
                    f2h(fmaf(accL[nt][j], 1.0f / 2048.0f, accH[nt][j]) + bb);
        }
    }
}

// ---------------------------------------------------------------------------
// Fused GIN MLP (fp16 MFMA): Zs = fp16(relu(relu(u@W1+b1)@W2+b2)).
// A-operands are raw fp16 loads (no conversion); weights fp16 hi/lo pairs.
// Fused per-column BN stats (f32, pre-rounding). M in LDS fp16 [64][72].
// ---------------------------------------------------------------------------
__global__ __launch_bounds__(256) void fused_mlp(
    const ushort* __restrict__ Us,
    const ushort* __restrict__ WT1hi, const ushort* __restrict__ WT1lo,
    const float* __restrict__ b1v,
    const ushort* __restrict__ WT2hi, const ushort* __restrict__ WT2lo,
    const float* __restrict__ b2v,
    ushort* __restrict__ Zs, float* __restrict__ stats)
{
    const int t = threadIdx.x;
    const int w = t >> 6;
    const int l = t & 63;
    const int lr = l & 15;   // A-row / B-col within 16-tile
    const int lk = l >> 4;   // k-group (8 elems each)

    __shared__ ushort Mh[64][72];
    __shared__ float red[2][4][4][16];

    // ---- stage 1: M = relu(u @ W1 + b1) ----
    half8 b1Hi[4][2], b1Lo[4][2];
    #pragma unroll
    for (int nt = 0; nt < 4; nt++)
        #pragma unroll
        for (int c = 0; c < 2; c++) {
            const int off = (nt * 16 + lr) * 64 + c * 32 + lk * 8;
            U4H8 uh, ul;
            uh.u = *(const uint4*)(WT1hi + off);
            ul.u = *(const uint4*)(WT1lo + off);
            b1Hi[nt][c] = uh.h;
            b1Lo[nt][c] = ul.h;
        }

    const int arow = blockIdx.x * 64 + w * 16 + lr;
    half8 aF[2];
    if (arow < Nn) {
        U4H8 v0, v1;
        v0.u = *(const uint4*)(Us + (size_t)arow * 64 + lk * 8);
        v1.u = *(const uint4*)(Us + (size_t)arow * 64 + 32 + lk * 8);
        aF[0] = v0.h;
        aF[1] = v1.h;
    } else {
        U4H8 z; z.u = make_uint4(0, 0, 0, 0);
        aF[0] = aF[1] = z.h;
    }

    f32x4 accH[4] = {}, accL[4] = {};
    #pragma unroll
    for (int nt = 0; nt < 4; nt++)
        #pragma unroll
        for (int c = 0; c < 2; c++) {
            accH[nt] = __builtin_amdgcn_mfma_f32_16x16x32_f16(
                aF[c], b1Hi[nt][c], accH[nt], 0, 0, 0);
            accL[nt] = __builtin_amdgcn_mfma_f32_16x16x32_f16(
                aF[c], b1Lo[nt][c], accL[nt], 0, 0, 0);
        }

    // M -> LDS (fp16); C/D layout: row = lk*4+j, col = nt*16+lr [m89]
    #pragma unroll
    for (int nt = 0; nt < 4; nt++) {
        const int ccol = nt * 16 + lr;
        const float bb = b1v[ccol];
        #pragma unroll
        for (int j = 0; j < 4; j++) {
            const int rloc = w * 16 + lk * 4 + j;
            const float m = fmaxf(fmaf(accL[nt][j], 1.0f / 2048.0f, accH[nt][j]) + bb, 0.f);
            Mh[rloc][ccol] = f2h(m);
        }
    }
    __syncthreads();

    // ---- stage 2: z = relu(M @ W2 + b2) ----
    half8 b2Hi[4][2], b2Lo[4][2];
    #pragma unroll
    for (int nt = 0; nt < 4; nt++)
        #pragma unroll
        for (int c = 0; c < 2; c++) {
            const int off = (nt * 16 + lr) * 64 + c * 32 + lk * 8;
            U4H8 uh, ul;
            uh.u = *(const uint4*)(WT2hi + off);
            ul.u = *(const uint4*)(WT2lo + off);
            b2Hi[nt][c] = uh.h;
            b2Lo[nt][c] = ul.h;
        }

    half8 a2F[2];
    #pragma unroll
    for (int c = 0; c < 2; c++) {
        U4H8 v;
        v.u = *(const uint4*)&Mh[w * 16 + lr][c * 32 + lk * 8];
        a2F[c] = v.h;
    }

    f32x4 acc2H[4] = {}, acc2L[4] = {};
    #pragma unroll
    for (int nt = 0; nt < 4; nt++)
        #pragma unroll
        for (int c = 0; c < 2; c++) {
            acc2H[nt] = __builtin_amdgcn_mfma_f32_16x16x32_f16(
                a2F[c], b2Hi[nt][c], acc2H[nt], 0, 0, 0);
            acc2L[nt] = __builtin_amdgcn_mfma_f32_16x16x32_f16(
                a2F[c], b2Lo[nt][c], acc2L[nt], 0, 0, 0);
        }

    float s[4], s2[4];
    #pragma unroll
    for (int nt = 0; nt < 4; nt++) {
        const int ccol = nt * 16 + lr;
        const float bb = b2v[ccol];
        s[nt] = 0.f; s2[nt] = 0.f;
        #pragma unroll
        for (int j = 0; j < 4; j++) {
            const int crow = blockIdx.x * 64 + w * 16 + lk * 4 + j;
            if (crow < Nn) {
                const float v = fmaxf(fmaf(acc2L[nt][j], 1.0f / 2048.0f, acc2H[nt][j]) + bb, 0.f);
                Zs[(size_t)crow * 64 + ccol] = f2h(v);
                s[nt] += v; s2[nt] += v * v;
            }
        }
    }

    #pragma unroll
    for (int nt = 0; nt < 4; nt++) {
        s[nt]  += __shfl_xor(s[nt], 16);  s[nt]  += __shfl_xor(s[nt], 32);
        s2[nt] += __shfl_xor(s2[nt], 16); s2[nt] += __shfl_xor(s2[nt], 32);
    }
    if (l < 16) {
        #pragma unroll
        for (int nt = 0; nt < 4; nt++) {
            red[0][w][nt][l] = s[nt];
            red[1][w][nt][l] = s2[nt];
        }
    }
    __syncthreads();
    if (t < 64) { // column = (t>>4)*16 + (t&15) = t
        float ts = 0.f, ts2 = 0.f;
        #pragma unroll
        for (int wv = 0; wv < 4; wv++) {
            ts  += red[0][wv][t >> 4][t & 15];
            ts2 += red[1][wv][t >> 4][t & 15];
        }
        atomicAdd(&stats[t], ts);
        atomicAdd(&stats[64 + t], ts2);
    }
}

// ---------------------------------------------------------------------------
// Bucketed CSR build.
// ---------------------------------------------------------------------------
__global__ __launch_bounds__(256) void bin_edges(
    const int* __restrict__ ei, int* __restrict__ gCursor,
    uint2* __restrict__ binned)
{
    __shared__ int hist[NB];
    __shared__ int base[NB];
    __shared__ int cur[NB];
    const int t = threadIdx.x;
    const int e0 = blockIdx.x * CHUNK;
    const int eEnd = min(e0 + CHUNK, Ee);
    if (t < NB) hist[t] = 0;
    __syncthreads();
    for (int e = e0 + t; e < eEnd; e += 256)
        atomicAdd(&hist[ei[Ee + e] >> 10], 1);
    __syncthreads();
    if (t < NB) {
        base[t] = atomicAdd(&gCursor[t], hist[t]);
        cur[t] = 0;
    }
    __syncthreads();
    for (int e = e0 + t; e < eEnd; e += 256) {
        const int s = ei[e];
        const int d = ei[Ee + e];
        const int b = d >> 10;
        const int pos = atomicAdd(&cur[b], 1);
        binned[(size_t)base[b] + pos] = make_uint2((uint)d, (uint)s);
    }
}

__global__ __launch_bounds__(128) void scan_buckets(
    const int* __restrict__ gCursor, int* __restrict__ bucketBase)
{
    __shared__ int sh[128];
    const int t = threadIdx.x;
    const int c = (t < NB) ? gCursor[t] - t * BCAP : 0;
    sh[t] = c;
    __syncthreads();
    for (int off = 1; off < 128; off <<= 1) {
        const int u = (t >= off) ? sh[t - off] : 0;
        __syncthreads();
        sh[t] += u;
        __syncthreads();
    }
    bucketBase[t] = sh[t] - c; // exclusive
}

__global__ __launch_bounds__(256) void build_csr(
    const uint2* __restrict__ binned, const int* __restrict__ gCursor,
    const int* __restrict__ bucketBase, int* __restrict__ rowptr,
    int* __restrict__ colidx)
{
    __shared__ int degS[1024];
    __shared__ int sh[256];
    __shared__ int colStage[BCAP];
    const int b = blockIdx.x;
    const int t = threadIdx.x;
    const int cnt = gCursor[b] - b * BCAP;
    const int base = bucketBase[b];
    const uint2* src = binned + (size_t)b * BCAP;

    for (int i = t; i < 1024; i += 256) degS[i] = 0;
    __syncthreads();
    for (int i = t; i < cnt; i += 256)
        atomicAdd(&degS[src[i].x & 1023], 1);
    __syncthreads();

    const int b4 = t * 4;
    const int v0 = degS[b4], v1 = degS[b4 + 1], v2 = degS[b4 + 2], v3 = degS[b4 + 3];
    const int sSum = v0 + v1 + v2 + v3;
    sh[t] = sSum;
    __syncthreads();
    for (int off = 1; off < 256; off <<= 1) {
        const int u = (t >= off) ? sh[t - off] : 0;
        __syncthreads();
        sh[t] += u;
        __syncthreads();
    }
    const int excl = sh[t] - sSum;
    const int p0 = excl, p1 = excl + v0, p2 = excl + v0 + v1, p3 = excl + v0 + v1 + v2;

    const int grow = b * 1024 + b4;
    if (grow + 3 <= Nn) {
        *(int4*)(rowptr + grow) = make_int4(base + p0, base + p1, base + p2, base + p3);
    } else {
        if (grow + 0 <= Nn) rowptr[grow + 0] = base + p0;
        if (grow + 1 <= Nn) rowptr[grow + 1] = base + p1;
        if (grow + 2 <= Nn) rowptr[grow + 2] = base + p2;
        if (grow + 3 <= Nn) rowptr[grow + 3] = base + p3;
    }

    degS[b4] = p0; degS[b4 + 1] = p1; degS[b4 + 2] = p2; degS[b4 + 3] = p3;
    __syncthreads();
    for (int i = t; i < cnt; i += 256) {
        const uint2 p = src[i];
        const int pos = atomicAdd(&degS[p.x & 1023], 1);
        colStage[pos] = (int)p.y;
    }
    __syncthreads();
    for (int i = t; i < cnt; i += 256) colidx[base + i] = colStage[i];
}

// ---------------------------------------------------------------------------
// Gather + deferred BN: u[r] = scale ∘ (z[r] + Σ_{j∈N(r)} z[j]) + (1+deg)*shift.
// 4-way unrolled independent gathers for memory-level parallelism.
// z fp16 in, u fp16 out, affine in f32. 8 lanes per row, 32 rows per block.
// ---------------------------------------------------------------------------
__global__ __launch_bounds__(256) void gather_bn(
    const int* __restrict__ rowptr, const int* __restrict__ col,
    const ushort* __restrict__ zs, const float* __restrict__ sc,
    ushort* __restrict__ us)
{
    __shared__ float scS[128];
    const int t = threadIdx.x;
    if (t < 128) scS[t] = sc[t];
    __syncthreads();

    const int r = blockIdx.x * 32 + (t >> 3);
    const int q = t & 7;
    const int beg = rowptr[r], end = rowptr[r + 1];
    float a[8];
    {
        const uint4 v = *(const uint4*)(zs + (size_t)r * 64 + q * 8); // self
        a[0] = h2f_lo(v.x); a[1] = h2f_hi(v.x);
        a[2] = h2f_lo(v.y); a[3] = h2f_hi(v.y);
        a[4] = h2f_lo(v.z); a[5] = h2f_hi(v.z);
        a[6] = h2f_lo(v.w); a[7] = h2f_hi(v.w);
    }
    int j = beg;
    const int end4 = beg + ((end - beg) & ~3);
    for (; j < end4; j += 4) {
        const int s0 = col[j], s1 = col[j + 1], s2 = col[j + 2], s3 = col[j + 3];
        const uint4 v0 = *(const uint4*)(zs + (size_t)s0 * 64 + q * 8);
        const uint4 v1 = *(const uint4*)(zs + (size_t)s1 * 64 + q * 8);
        const uint4 v2 = *(const uint4*)(zs + (size_t)s2 * 64 + q * 8);
        const uint4 v3 = *(const uint4*)(zs + (size_t)s3 * 64 + q * 8);
        a[0] += h2f_lo(v0.x) + h2f_lo(v1.x) + h2f_lo(v2.x) + h2f_lo(v3.x);
        a[1] += h2f_hi(v0.x) + h2f_hi(v1.x) + h2f_hi(v2.x) + h2f_hi(v3.x);
        a[2] += h2f_lo(v0.y) + h2f_lo(v1.y) + h2f_lo(v2.y) + h2f_lo(v3.y);
        a[3] += h2f_hi(v0.y) + h2f_hi(v1.y) + h2f_hi(v2.y) + h2f_hi(v3.y);
        a[4] += h2f_lo(v0.z) + h2f_lo(v1.z) + h2f_lo(v2.z) + h2f_lo(v3.z);
        a[5] += h2f_hi(v0.z) + h2f_hi(v1.z) + h2f_hi(v2.z) + h2f_hi(v3.z);
        a[6] += h2f_lo(v0.w) + h2f_lo(v1.w) + h2f_lo(v2.w) + h2f_lo(v3.w);
        a[7] += h2f_hi(v0.w) + h2f_hi(v1.w) + h2f_hi(v2.w) + h2f_hi(v3.w);
    }
    for (; j < end; j++) {
        const int s = col[j];
        const uint4 v = *(const uint4*)(zs + (size_t)s * 64 + q * 8);
        a[0] += h2f_lo(v.x); a[1] += h2f_hi(v.x);
        a[2] += h2f_lo(v.y); a[3] += h2f_hi(v.y);
        a[4] += h2f_lo(v.z); a[5] += h2f_hi(v.z);
        a[6] += h2f_lo(v.w); a[7] += h2f_hi(v.w);
    }
    const float dgf = (float)(end - beg + 1);
    float o[8];
    #pragma unroll
    for (int i = 0; i < 8; i++)
        o[i] = fmaf(scS[q * 8 + i], a[i], dgf * scS[64 + q * 8 + i]);
    uint4 p;
    p.x = pack2h(o[0], o[1]); p.y = pack2h(o[2], o[3]);
    p.z = pack2h(o[4], o[5]); p.w = pack2h(o[6], o[7]);
    *(uint4*)(us + (size_t)r * 64 + q * 8) = p;
}

// Compute scale/shift from stats -> sc (current) + sc5[layer]; zero stats.
__global__ void bn_finalize(
    float* __restrict__ stats, const float* __restrict__ gamma,
    const float* __restrict__ beta, float* __restrict__ sc,
    float* __restrict__ sc5, int layer)
{
    const int c = threadIdx.x; // 64 threads, 1 block
    const float mean = stats[c] * (1.0f / Nn);
    const float var = stats[64 + c] * (1.0f / Nn) - mean * mean;
    const float scale = gamma[layer * 64 + c] * rsqrtf(var + 1e-5f);
    const float shift = beta[layer * 64 + c] - mean * scale;
    sc[c] = scale;
    sc[64 + c] = shift;
    sc5[layer * 128 + c] = scale;
    sc5[layer * 128 + 64 + c] = shift;
    stats[c] = 0.f;
    stats[64 + c] = 0.f;
}

// ---------------------------------------------------------------------------
// Per-graph raw-z column sums (fp16 in, f32 accum). 8 blocks/graph.
// ---------------------------------------------------------------------------
__global__ __launch_bounds__(256) void pool_z(
    const ushort* __restrict__ zs, const int* __restrict__ batch,
    float* __restrict__ poolZ)
{
    const int g = blockIdx.x >> 3;
    const int sub = blockIdx.x & 7;
    const int lo = lower_bound_i(batch, Nn, g);
    const int hi = lower_bound_i(batch, Nn, g + 1);
    const int t = threadIdx.x;
    const int cq = t & 15;                 // cols cq*4 .. +3
    const int rg = (t >> 4) + sub * 16;    // 0..127
    float acc[4] = {};
    for (int row = lo + rg; row < hi; row += 128) {
        const uint2 p = *(const uint2*)(zs + (size_t)row * 64 + cq * 4);
        acc[0] += h2f_lo(p.x); acc[1] += h2f_hi(p.x);
        acc[2] += h2f_lo(p.y); acc[3] += h2f_hi(p.y);
    }
    __shared__ float red[16][16][4];
    #pragma unroll
    for (int i = 0; i < 4; i++) red[t >> 4][cq][i] = acc[i];
    __syncthreads();
    if (t < 64) {
        const int c2 = t >> 2, j = t & 3;
        float s = 0.f;
        #pragma unroll
        for (int r = 0; r < 16; r++) s += red[r][c2][j];
        atomicAdd(&poolZ[g * 64 + c2 * 4 + j], s);
    }
}

// ---------------------------------------------------------------------------
// Final pooled transform across all layers:
// pooled[g][l*64+c] = sc5[l][c]*poolZ[l][g][c] + cnt[g]*sc5[l][64+c]
// ---------------------------------------------------------------------------
__global__ __launch_bounds__(256) void final_pool(
    const float* __restrict__ sc5, const float* __restrict__ poolZ,
    const int* __restrict__ cnt, float* __restrict__ pooled)
{
    const int idx = blockIdx.x * 256 + threadIdx.x; // 40960
    const int c = idx & 63;
    const int g = (idx >> 6) & 127;
    const int l = idx >> 13;
    pooled[g * PDim + l * 64 + c] =
        sc5[l * 128 + c] * poolZ[(size_t)l * Gg * 64 + g * 64 + c]
        + (float)cnt[g] * sc5[l * 128 + 64 + c];
}

// ---------------------------------------------------------------------------
// Proj head GEMM: (128,320)@(320,320)+b (f32, small).
// ---------------------------------------------------------------------------
template<bool RELU>
__global__ __launch_bounds__(256) void proj(
    const float* __restrict__ X, const float* __restrict__ W,
    const float* __restrict__ bias, float* __restrict__ Y)
{
    const int idx = blockIdx.x * 256 + threadIdx.x; // 40960 exact
    const int r = idx / PDim;
    const int c = idx - r * PDim;
    float acc = bias[c];
    #pragma unroll 8
    for (int k = 0; k < PDim; k++)
        acc = fmaf(X[r * PDim + k], W[k * PDim + c], acc);
    if constexpr (RELU) acc = fmaxf(acc, 0.f);
    Y[idx] = acc;
}

// ---------------------------------------------------------------------------
// Row-wise l2 normalize.
// ---------------------------------------------------------------------------
__global__ __launch_bounds__(64) void l2norm_rows(
    const float* __restrict__ X, float* __restrict__ out)
{
    const int r = blockIdx.x;
    const int l = threadIdx.x;
    float v[5];
    float s = 0.f;
    #pragma unroll
    for (int i = 0; i < 5; i++) {
        v[i] = X[r * PDim + i * 64 + l];
        s += v[i] * v[i];
    }
    #pragma unroll
    for (int off = 32; off > 0; off >>= 1) s += __shfl_down(s, off);
    s = __shfl(s, 0);
    const float d = fmaxf(sqrtf(s), 1e-12f);
    #pragma unroll
    for (int i = 0; i < 5; i++)
        out[r * PDim + i * 64 + l] = v[i] / d;
}

// ---------------------------------------------------------------------------
extern "C" void kernel_launch(void* const* d_in, const int* in_sizes, int n_in,
                              void* d_out, int out_size, void* d_ws, size_t ws_size,
                              hipStream_t stream)
{
    const float* x     = (const float*)d_in[0];
    const int*   ei    = (const int*)d_in[1];
    const int*   batch = (const int*)d_in[2];
    const float* Ws    = (const float*)d_in[3];
    const float* bs    = (const float*)d_in[4];
    const float* W1    = (const float*)d_in[5];
    const float* b1    = (const float*)d_in[6];
    const float* W2    = (const float*)d_in[7];
    const float* b2    = (const float*)d_in[8];
    const float* gamma = (const float*)d_in[9];
    const float* beta  = (const float*)d_in[10];
    const float* Wp1   = (const float*)d_in[11];
    const float* bp1   = (const float*)d_in[12];
    const float* Wp2   = (const float*)d_in[13];
    const float* bp2   = (const float*)d_in[14];
    float* out = (float*)d_out;

    // workspace
    ushort* Us = (ushort*)d_ws;                   // u  fp16 (N*64)  12.8MB
    ushort* Zs = Us + (size_t)Nn * 64;            // z  fp16         12.8MB
    ushort* WThi = Zs + (size_t)Nn * 64;          // 11*4096 fp16
    ushort* WTlo = WThi + 11 * 4096;
    float* pooled = (float*)(WTlo + 11 * 4096);   // (G,320)
    float* ytmp   = pooled + (size_t)Gg * PDim;
    float* ypro   = ytmp + (size_t)Gg * PDim;
    float* stats  = ypro + (size_t)Gg * PDim;     // 128
    float* sc     = stats + 128;                  // 128
    float* sc5    = sc + 128;                     // 5*128
    float* poolZ  = sc5 + 5 * 128;                // 5*G*64
    int* cnt    = (int*)(poolZ + 5 * Gg * 64);    // 128
    int* rowptr = cnt + 128;                      // Nn+1
    int* colidx = rowptr + Nn + 1;                // Ee
    int* gCursor = colidx + Ee;                   // 128 (NB used)
    int* bucketBase = gCursor + 128;              // 128
    size_t woff = (size_t)((bucketBase + 128) - (int*)d_ws);
    woff = (woff + 1) & ~(size_t)1;
    uint2* binned = (uint2*)((int*)d_ws + woff);  // NB*BCAP*8B = 12.6MB

    const int gemmGrid = (Nn + 63) / 64;          // 1563

    hipMemsetAsync(stats, 0, 128 * sizeof(float), stream);
    hipMemsetAsync(poolZ, 0, 5 * Gg * 64 * sizeof(float), stream);

    init_csr<<<1, 128, 0, stream>>>(batch, gCursor, cnt, sc);
    conv_weights<<<11, 256, 0, stream>>>(Ws, W1, W2, WThi, WTlo);

    // bucketed CSR build
    bin_edges<<<NBLK_A, 256, 0, stream>>>(ei, gCursor, binned);
    scan_buckets<<<1, 128, 0, stream>>>(gCursor, bucketBase);
    build_csr<<<NB, 256, 0, stream>>>(binned, gCursor, bucketBase, rowptr, colidx);

    // encoder: Zs = fp16(x @ Ws + bs)   (raw z_0; BN identity in sc)
    gemm_enc<<<gemmGrid, 256, 0, stream>>>(x, WThi, WTlo, bs, Zs);

    for (int l = 0; l < Ll; l++) {
        // u = BN_{l-1} applied to inclusive sum of raw z (affine distributes)
        gather_bn<<<Nn / 32, 256, 0, stream>>>(rowptr, colidx, Zs, sc, Us);
        fused_mlp<<<gemmGrid, 256, 0, stream>>>(
            Us,
            WThi + (size_t)(1 + l) * 4096, WTlo + (size_t)(1 + l) * 4096,
            b1 + (size_t)l * 64,
            WThi + (size_t)(6 + l) * 4096, WTlo + (size_t)(6 + l) * 4096,
            b2 + (size_t)l * 64,
            Zs, stats);
        bn_finalize<<<1, 64, 0, stream>>>(stats, gamma, beta, sc, sc5, l);
        pool_z<<<Gg * 8, 256, 0, stream>>>(Zs, batch, poolZ + (size_t)l * Gg * 64);
    }

    final_pool<<<160, 256, 0, stream>>>(sc5, poolZ, cnt, pooled);

    // proj head (f32)
    proj<true><<<160, 256, 0, stream>>>(pooled, Wp1, bp1, ytmp);
    proj<false><<<160, 256, 0, stream>>>(ytmp, Wp2, bp2, ypro);

    l2norm_rows<<<Gg, 64, 0, stream>>>(ypro, out);               // out0
    l2norm_rows<<<Gg, 64, 0, stream>>>(pooled, out + Gg * PDim); // out1
}

// Round 14
// 572.087 us; speedup vs baseline: 1.7211x; 1.1052x over previous
//
#include <hip/hip_runtime.h>
#include <hip/hip_bf16.h>
#include <hip/hip_fp16.h>

constexpr int Nn = 100000;
constexpr int Ee = 1200000;
constexpr int Ll = 5;
constexpr int Gg = 128;
constexpr int PDim = 320; // L*D
constexpr int GG = (Nn + 63) / 64; // 1563 gemm blocks

// bucketed CSR build params
constexpr int NB    = 98;     // buckets of 1024 rows (dst >> 10)
constexpr int BCAP  = 16384;  // per-bucket edge capacity
constexpr int CHUNK = 4096;   // edges per bin_edges block
constexpr int NBLK_A = (Ee + CHUNK - 1) / CHUNK; // 293

typedef float f32x4 __attribute__((ext_vector_type(4)));
typedef _Float16 half8 __attribute__((ext_vector_type(8)));

union U4H8 { uint4 u; half8 h; };

__device__ inline ushort f2h(float f) {
    const __half h = __float2half(f);
    return *(const ushort*)&h;
}
__device__ inline uint pack2h(float lo, float hi) {
    return (uint)f2h(lo) | ((uint)f2h(hi) << 16);
}
__device__ inline float h2f_lo(uint u) {
    const ushort s = (ushort)(u & 0xffffu);
    return __half2float(*(const __half*)&s);
}
__device__ inline float h2f_hi(uint u) {
    const ushort s = (ushort)(u >> 16);
    return __half2float(*(const __half*)&s);
}

__device__ inline int lower_bound_i(const int* __restrict__ a, int n, int v)
{
    int lo = 0, hi = n;
    while (lo < hi) {
        const int m = (lo + hi) >> 1;
        if (a[m] < v) lo = m + 1; else hi = m;
    }
    return lo;
}

// ---------------------------------------------------------------------------
// init: gCursor for buckets, per-graph node counts, identity BN sc.
// ---------------------------------------------------------------------------
__global__ void init_csr(const int* __restrict__ batch, int* __restrict__ gCursor,
                         int* __restrict__ cnt, float* __restrict__ sc)
{
    const int t = threadIdx.x; // 128
    if (t < NB) gCursor[t] = t * BCAP;
    {
        const int lo = lower_bound_i(batch, Nn, t);
        const int hi = lower_bound_i(batch, Nn, t + 1);
        cnt[t] = hi - lo;
    }
    if (t < 64) { sc[t] = 1.f; sc[64 + t] = 0.f; }
}

// ---------------------------------------------------------------------------
// Weight conversion: 11 64x64 f32 matrices -> TRANSPOSED fp16 hi + fp16
// (residual*2048) lo. 22-bit effective weight precision.
// Block m: 0=Ws, 1..5=W1[m-1], 6..10=W2[m-6].
// ---------------------------------------------------------------------------
__global__ __launch_bounds__(256) void conv_weights(
    const float* __restrict__ Ws, const float* __restrict__ W1,
    const float* __restrict__ W2, ushort* __restrict__ WThi,
    ushort* __restrict__ WTlo)
{
    const int m = blockIdx.x;
    const float* src = (m == 0) ? Ws
                     : (m <= 5) ? W1 + (size_t)(m - 1) * 4096
                                : W2 + (size_t)(m - 6) * 4096;
    ushort* dh = WThi + (size_t)m * 4096;
    ushort* dl = WTlo + (size_t)m * 4096;
    const int t = threadIdx.x;
    const int col = t & 63;
    const int k0 = (t >> 6) * 16;
    #pragma unroll
    for (int i = 0; i < 16; i++) {
        const int k = k0 + i;
        const float w = src[k * 64 + col];
        const ushort h = f2h(w);
        dh[col * 64 + k] = h;
        const float resid = (w - h2f_lo((uint)h)) * 2048.0f;
        dl[col * 64 + k] = f2h(resid);
    }
}

// ---------------------------------------------------------------------------
// Encoder GEMM (fp16 MFMA): Zs = fp16(x @ Ws + bs).
// x split into fp16 hi + fp16 lo*2048; acc = Ah@Wh + (Ah@Wl + Al@Wh)/2048.
// ---------------------------------------------------------------------------
__global__ __launch_bounds__(256) void gemm_enc(
    const float* __restrict__ A1,
    const ushort* __restrict__ WThi, const ushort* __restrict__ WTlo,
    const float* __restrict__ bias, ushort* __restrict__ Ys)
{
    const int t = threadIdx.x;
    const int w = t >> 6;
    const int l = t & 63;
    const int lr = l & 15;
    const int lk = l >> 4;

    half8 bHi[4][2], bLo[4][2];
    #pragma unroll
    for (int nt = 0; nt < 4; nt++)
        #pragma unroll
        for (int c = 0; c < 2; c++) {
            const int off = (nt * 16 + lr) * 64 + c * 32 + lk * 8;
            U4H8 uh, ul;
            uh.u = *(const uint4*)(WThi + off);
            ul.u = *(const uint4*)(WTlo + off);
            bHi[nt][c] = uh.h;
            bLo[nt][c] = ul.h;
        }

    const int arow = blockIdx.x * 64 + w * 16 + lr;
    half8 aHi[2], aLo[2];
    if (arow < Nn) {
        #pragma unroll
        for (int c = 0; c < 2; c++) {
            const float* p1 = A1 + (size_t)arow * 64 + c * 32 + lk * 8;
            U4H8 rh, rl;
            #pragma unroll
            for (int i = 0; i < 8; i++) {
                const float xv = p1[i];
                const _Float16 xh = (_Float16)xv;
                rh.h[i] = xh;
                rl.h[i] = (_Float16)((xv - (float)xh) * 2048.0f);
            }
            aHi[c] = rh.h;
            aLo[c] = rl.h;
        }
    } else {
        U4H8 z; z.u = make_uint4(0, 0, 0, 0);
        aHi[0] = aHi[1] = z.h;
        aLo[0] = aLo[1] = z.h;
    }

    f32x4 accH[4] = {}, accL[4] = {};
    #pragma unroll
    for (int nt = 0; nt < 4; nt++)
        #pragma unroll
        for (int c = 0; c < 2; c++) {
            accH[nt] = __builtin_amdgcn_mfma_f32_16x16x32_f16(
                aHi[c], bHi[nt][c], accH[nt], 0, 0, 0);
            accL[nt] = __builtin_amdgcn_mfma_f32_16x16x32_f16(
                aHi[c], bLo[nt][c], accL[nt], 0, 0, 0);
            accL[nt] = __builtin_amdgcn_mfma_f32_16x16x32_f16(
                aLo[c], bHi[nt][c], accL[nt], 0, 0, 0);
        }

    #pragma unroll
    for (int nt = 0; nt < 4; nt++) {
        const int ccol = nt * 16 + lr;
        const float bb = bias[ccol];
        #pragma unroll
        for (int j = 0; j < 4; j++) {
            const int crow = blockIdx.x * 64 + w * 16 + lk * 4 + j;
            if (crow < Nn)
                Ys[(size_t)crow * 64 + ccol] =
                    f2h(fmaf(accL[nt][j], 1.0f / 2048.0f, accH[nt][j]) + bb);
        }
    }
}

// ---------------------------------------------------------------------------
// Fused GIN MLP (fp16 MFMA): Zs = fp16(relu(relu(u@W1+b1)@W2+b2)).
// Per-column BN stats -> per-block PARTIAL writes (spart[blk][128], no
// same-address atomics; reduced by reduce_stats). M in LDS fp16 [64][72].
// ---------------------------------------------------------------------------
__global__ __launch_bounds__(256) void fused_mlp(
    const ushort* __restrict__ Us,
    const ushort* __restrict__ WT1hi, const ushort* __restrict__ WT1lo,
    const float* __restrict__ b1v,
    const ushort* __restrict__ WT2hi, const ushort* __restrict__ WT2lo,
    const float* __restrict__ b2v,
    ushort* __restrict__ Zs, float* __restrict__ spart)
{
    const int t = threadIdx.x;
    const int w = t >> 6;
    const int l = t & 63;
    const int lr = l & 15;   // A-row / B-col within 16-tile
    const int lk = l >> 4;   // k-group (8 elems each)

    __shared__ ushort Mh[64][72];
    __shared__ float red[2][4][4][16];

    // ---- stage 1: M = relu(u @ W1 + b1) ----
    half8 b1Hi[4][2], b1Lo[4][2];
    #pragma unroll
    for (int nt = 0; nt < 4; nt++)
        #pragma unroll
        for (int c = 0; c < 2; c++) {
            const int off = (nt * 16 + lr) * 64 + c * 32 + lk * 8;
            U4H8 uh, ul;
            uh.u = *(const uint4*)(WT1hi + off);
            ul.u = *(const uint4*)(WT1lo + off);
            b1Hi[nt][c] = uh.h;
            b1Lo[nt][c] = ul.h;
        }

    const int arow = blockIdx.x * 64 + w * 16 + lr;
    half8 aF[2];
    if (arow < Nn) {
        U4H8 v0, v1;
        v0.u = *(const uint4*)(Us + (size_t)arow * 64 + lk * 8);
        v1.u = *(const uint4*)(Us + (size_t)arow * 64 + 32 + lk * 8);
        aF[0] = v0.h;
        aF[1] = v1.h;
    } else {
        U4H8 z; z.u = make_uint4(0, 0, 0, 0);
        aF[0] = aF[1] = z.h;
    }

    f32x4 accH[4] = {}, accL[4] = {};
    #pragma unroll
    for (int nt = 0; nt < 4; nt++)
        #pragma unroll
        for (int c = 0; c < 2; c++) {
            accH[nt] = __builtin_amdgcn_mfma_f32_16x16x32_f16(
                aF[c], b1Hi[nt][c], accH[nt], 0, 0, 0);
            accL[nt] = __builtin_amdgcn_mfma_f32_16x16x32_f16(
                aF[c], b1Lo[nt][c], accL[nt], 0, 0, 0);
        }

    // M -> LDS (fp16); C/D layout: row = lk*4+j, col = nt*16+lr [m89]
    #pragma unroll
    for (int nt = 0; nt < 4; nt++) {
        const int ccol = nt * 16 + lr;
        const float bb = b1v[ccol];
        #pragma unroll
        for (int j = 0; j < 4; j++) {
            const int rloc = w * 16 + lk * 4 + j;
            const float m = fmaxf(fmaf(accL[nt][j], 1.0f / 2048.0f, accH[nt][j]) + bb, 0.f);
            Mh[rloc][ccol] = f2h(m);
        }
    }
    __syncthreads();

    // ---- stage 2: z = relu(M @ W2 + b2) ----
    half8 b2Hi[4][2], b2Lo[4][2];
    #pragma unroll
    for (int nt = 0; nt < 4; nt++)
        #pragma unroll
        for (int c = 0; c < 2; c++) {
            const int off = (nt * 16 + lr) * 64 + c * 32 + lk * 8;
            U4H8 uh, ul;
            uh.u = *(const uint4*)(WT2hi + off);
            ul.u = *(const uint4*)(WT2lo + off);
            b2Hi[nt][c] = uh.h;
            b2Lo[nt][c] = ul.h;
        }

    half8 a2F[2];
    #pragma unroll
    for (int c = 0; c < 2; c++) {
        U4H8 v;
        v.u = *(const uint4*)&Mh[w * 16 + lr][c * 32 + lk * 8];
        a2F[c] = v.h;
    }

    f32x4 acc2H[4] = {}, acc2L[4] = {};
    #pragma unroll
    for (int nt = 0; nt < 4; nt++)
        #pragma unroll
        for (int c = 0; c < 2; c++) {
            acc2H[nt] = __builtin_amdgcn_mfma_f32_16x16x32_f16(
                a2F[c], b2Hi[nt][c], acc2H[nt], 0, 0, 0);
            acc2L[nt] = __builtin_amdgcn_mfma_f32_16x16x32_f16(
                a2F[c], b2Lo[nt][c], acc2L[nt], 0, 0, 0);
        }

    float s[4], s2[4];
    #pragma unroll
    for (int nt = 0; nt < 4; nt++) {
        const int ccol = nt * 16 + lr;
        const float bb = b2v[ccol];
        s[nt] = 0.f; s2[nt] = 0.f;
        #pragma unroll
        for (int j = 0; j < 4; j++) {
            const int crow = blockIdx.x * 64 + w * 16 + lk * 4 + j;
            if (crow < Nn) {
                const float v = fmaxf(fmaf(acc2L[nt][j], 1.0f / 2048.0f, acc2H[nt][j]) + bb, 0.f);
                Zs[(size_t)crow * 64 + ccol] = f2h(v);
                s[nt] += v; s2[nt] += v * v;
            }
        }
    }

    #pragma unroll
    for (int nt = 0; nt < 4; nt++) {
        s[nt]  += __shfl_xor(s[nt], 16);  s[nt]  += __shfl_xor(s[nt], 32);
        s2[nt] += __shfl_xor(s2[nt], 16); s2[nt] += __shfl_xor(s2[nt], 32);
    }
    if (l < 16) {
        #pragma unroll
        for (int nt = 0; nt < 4; nt++) {
            red[0][w][nt][l] = s[nt];
            red[1][w][nt][l] = s2[nt];
        }
    }
    __syncthreads();
    if (t < 64) { // column = (t>>4)*16 + (t&15) = t
        float ts = 0.f, ts2 = 0.f;
        #pragma unroll
        for (int wv = 0; wv < 4; wv++) {
            ts  += red[0][wv][t >> 4][t & 15];
            ts2 += red[1][wv][t >> 4][t & 15];
        }
        // coalesced per-block partial write (no atomics)
        spart[(size_t)blockIdx.x * 128 + t] = ts;
        spart[(size_t)blockIdx.x * 128 + 64 + t] = ts2;
    }
}

// ---------------------------------------------------------------------------
// Reduce per-block stats partials: stats[c] += sum_b spart[b][c].
// 16 blocks x 256 threads; coalesced reads; 16-way atomic contention only.
// ---------------------------------------------------------------------------
__global__ __launch_bounds__(256) void reduce_stats(
    const float* __restrict__ spart, float* __restrict__ stats)
{
    const int t = threadIdx.x;
    const int col = t & 127;
    const int half = t >> 7; // 0 or 1
    const int r0 = blockIdx.x * 98;
    const int r1 = min(r0 + 98, GG);
    float acc = 0.f;
    for (int r = r0 + half; r < r1; r += 2)
        acc += spart[(size_t)r * 128 + col];
    atomicAdd(&stats[col], acc);
}

// ---------------------------------------------------------------------------
// Bucketed CSR build.
// ---------------------------------------------------------------------------
__global__ __launch_bounds__(256) void bin_edges(
    const int* __restrict__ ei, int* __restrict__ gCursor,
    uint2* __restrict__ binned)
{
    __shared__ int hist[NB];
    __shared__ int base[NB];
    __shared__ int cur[NB];
    const int t = threadIdx.x;
    const int e0 = blockIdx.x * CHUNK;
    const int eEnd = min(e0 + CHUNK, Ee);
    if (t < NB) hist[t] = 0;
    __syncthreads();
    for (int e = e0 + t; e < eEnd; e += 256)
        atomicAdd(&hist[ei[Ee + e] >> 10], 1);
    __syncthreads();
    if (t < NB) {
        base[t] = atomicAdd(&gCursor[t], hist[t]);
        cur[t] = 0;
    }
    __syncthreads();
    for (int e = e0 + t; e < eEnd; e += 256) {
        const int s = ei[e];
        const int d = ei[Ee + e];
        const int b = d >> 10;
        const int pos = atomicAdd(&cur[b], 1);
        binned[(size_t)base[b] + pos] = make_uint2((uint)d, (uint)s);
    }
}

__global__ __launch_bounds__(128) void scan_buckets(
    const int* __restrict__ gCursor, int* __restrict__ bucketBase)
{
    __shared__ int sh[128];
    const int t = threadIdx.x;
    const int c = (t < NB) ? gCursor[t] - t * BCAP : 0;
    sh[t] = c;
    __syncthreads();
    for (int off = 1; off < 128; off <<= 1) {
        const int u = (t >= off) ? sh[t - off] : 0;
        __syncthreads();
        sh[t] += u;
        __syncthreads();
    }
    bucketBase[t] = sh[t] - c; // exclusive
}

__global__ __launch_bounds__(256) void build_csr(
    const uint2* __restrict__ binned, const int* __restrict__ gCursor,
    const int* __restrict__ bucketBase, int* __restrict__ rowptr,
    int* __restrict__ colidx)
{
    __shared__ int degS[1024];
    __shared__ int sh[256];
    __shared__ int colStage[BCAP];
    const int b = blockIdx.x;
    const int t = threadIdx.x;
    const int cnt = gCursor[b] - b * BCAP;
    const int base = bucketBase[b];
    const uint2* src = binned + (size_t)b * BCAP;

    for (int i = t; i < 1024; i += 256) degS[i] = 0;
    __syncthreads();
    for (int i = t; i < cnt; i += 256)
        atomicAdd(&degS[src[i].x & 1023], 1);
    __syncthreads();

    const int b4 = t * 4;
    const int v0 = degS[b4], v1 = degS[b4 + 1], v2 = degS[b4 + 2], v3 = degS[b4 + 3];
    const int sSum = v0 + v1 + v2 + v3;
    sh[t] = sSum;
    __syncthreads();
    for (int off = 1; off < 256; off <<= 1) {
        const int u = (t >= off) ? sh[t - off] : 0;
        __syncthreads();
        sh[t] += u;
        __syncthreads();
    }
    const int excl = sh[t] - sSum;
    const int p0 = excl, p1 = excl + v0, p2 = excl + v0 + v1, p3 = excl + v0 + v1 + v2;

    const int grow = b * 1024 + b4;
    if (grow + 3 <= Nn) {
        *(int4*)(rowptr + grow) = make_int4(base + p0, base + p1, base + p2, base + p3);
    } else {
        if (grow + 0 <= Nn) rowptr[grow + 0] = base + p0;
        if (grow + 1 <= Nn) rowptr[grow + 1] = base + p1;
        if (grow + 2 <= Nn) rowptr[grow + 2] = base + p2;
        if (grow + 3 <= Nn) rowptr[grow + 3] = base + p3;
    }

    degS[b4] = p0; degS[b4 + 1] = p1; degS[b4 + 2] = p2; degS[b4 + 3] = p3;
    __syncthreads();
    for (int i = t; i < cnt; i += 256) {
        const uint2 p = src[i];
        const int pos = atomicAdd(&degS[p.x & 1023], 1);
        colStage[pos] = (int)p.y;
    }
    __syncthreads();
    for (int i = t; i < cnt; i += 256) colidx[base + i] = colStage[i];
}

// ---------------------------------------------------------------------------
// Gather + deferred BN: u[r] = scale ∘ (z[r] + Σ_{j∈N(r)} z[j]) + (1+deg)*shift.
// 4-way unrolled independent gathers for memory-level parallelism.
// z fp16 in, u fp16 out, affine in f32. 8 lanes per row, 32 rows per block.
// ---------------------------------------------------------------------------
__global__ __launch_bounds__(256) void gather_bn(
    const int* __restrict__ rowptr, const int* __restrict__ col,
    const ushort* __restrict__ zs, const float* __restrict__ sc,
    ushort* __restrict__ us)
{
    __shared__ float scS[128];
    const int t = threadIdx.x;
    if (t < 128) scS[t] = sc[t];
    __syncthreads();

    const int r = blockIdx.x * 32 + (t >> 3);
    const int q = t & 7;
    const int beg = rowptr[r], end = rowptr[r + 1];
    float a[8];
    {
        const uint4 v = *(const uint4*)(zs + (size_t)r * 64 + q * 8); // self
        a[0] = h2f_lo(v.x); a[1] = h2f_hi(v.x);
        a[2] = h2f_lo(v.y); a[3] = h2f_hi(v.y);
        a[4] = h2f_lo(v.z); a[5] = h2f_hi(v.z);
        a[6] = h2f_lo(v.w); a[7] = h2f_hi(v.w);
    }
    int j = beg;
    const int end4 = beg + ((end - beg) & ~3);
    for (; j < end4; j += 4) {
        const int s0 = col[j], s1 = col[j + 1], s2 = col[j + 2], s3 = col[j + 3];
        const uint4 v0 = *(const uint4*)(zs + (size_t)s0 * 64 + q * 8);
        const uint4 v1 = *(const uint4*)(zs + (size_t)s1 * 64 + q * 8);
        const uint4 v2 = *(const uint4*)(zs + (size_t)s2 * 64 + q * 8);
        const uint4 v3 = *(const uint4*)(zs + (size_t)s3 * 64 + q * 8);
        a[0] += h2f_lo(v0.x) + h2f_lo(v1.x) + h2f_lo(v2.x) + h2f_lo(v3.x);
        a[1] += h2f_hi(v0.x) + h2f_hi(v1.x) + h2f_hi(v2.x) + h2f_hi(v3.x);
        a[2] += h2f_lo(v0.y) + h2f_lo(v1.y) + h2f_lo(v2.y) + h2f_lo(v3.y);
        a[3] += h2f_hi(v0.y) + h2f_hi(v1.y) + h2f_hi(v2.y) + h2f_hi(v3.y);
        a[4] += h2f_lo(v0.z) + h2f_lo(v1.z) + h2f_lo(v2.z) + h2f_lo(v3.z);
        a[5] += h2f_hi(v0.z) + h2f_hi(v1.z) + h2f_hi(v2.z) + h2f_hi(v3.z);
        a[6] += h2f_lo(v0.w) + h2f_lo(v1.w) + h2f_lo(v2.w) + h2f_lo(v3.w);
        a[7] += h2f_hi(v0.w) + h2f_hi(v1.w) + h2f_hi(v2.w) + h2f_hi(v3.w);
    }
    for (; j < end; j++) {
        const int s = col[j];
        const uint4 v = *(const uint4*)(zs + (size_t)s * 64 + q * 8);
        a[0] += h2f_lo(v.x); a[1] += h2f_hi(v.x);
        a[2] += h2f_lo(v.y); a[3] += h2f_hi(v.y);
        a[4] += h2f_lo(v.z); a[5] += h2f_hi(v.z);
        a[6] += h2f_lo(v.w); a[7] += h2f_hi(v.w);
    }
    const float dgf = (float)(end - beg + 1);
    float o[8];
    #pragma unroll
    for (int i = 0; i < 8; i++)
        o[i] = fmaf(scS[q * 8 + i], a[i], dgf * scS[64 + q * 8 + i]);
    uint4 p;
    p.x = pack2h(o[0], o[1]); p.y = pack2h(o[2], o[3]);
    p.z = pack2h(o[4], o[5]); p.w = pack2h(o[6], o[7]);
    *(uint4*)(us + (size_t)r * 64 + q * 8) = p;
}

// Compute scale/shift from stats -> sc (current) + sc5[layer]; zero stats.
__global__ void bn_finalize(
    float* __restrict__ stats, const float* __restrict__ gamma,
    const float* __restrict__ beta, float* __restrict__ sc,
    float* __restrict__ sc5, int layer)
{
    const int c = threadIdx.x; // 64 threads, 1 block
    const float mean = stats[c] * (1.0f / Nn);
    const float var = stats[64 + c] * (1.0f / Nn) - mean * mean;
    const float scale = gamma[layer * 64 + c] * rsqrtf(var + 1e-5f);
    const float shift = beta[layer * 64 + c] - mean * scale;
    sc[c] = scale;
    sc[64 + c] = shift;
    sc5[layer * 128 + c] = scale;
    sc5[layer * 128 + 64 + c] = shift;
    stats[c] = 0.f;
    stats[64 + c] = 0.f;
}

// ---------------------------------------------------------------------------
// Per-graph raw-z column sums (fp16 in, f32 accum). 8 blocks/graph.
// ---------------------------------------------------------------------------
__global__ __launch_bounds__(256) void pool_z(
    const ushort* __restrict__ zs, const int* __restrict__ batch,
    float* __restrict__ poolZ)
{
    const int g = blockIdx.x >> 3;
    const int sub = blockIdx.x & 7;
    const int lo = lower_bound_i(batch, Nn, g);
    const int hi = lower_bound_i(batch, Nn, g + 1);
    const int t = threadIdx.x;
    const int cq = t & 15;                 // cols cq*4 .. +3
    const int rg = (t >> 4) + sub * 16;    // 0..127
    float acc[4] = {};
    for (int row = lo + rg; row < hi; row += 128) {
        const uint2 p = *(const uint2*)(zs + (size_t)row * 64 + cq * 4);
        acc[0] += h2f_lo(p.x); acc[1] += h2f_hi(p.x);
        acc[2] += h2f_lo(p.y); acc[3] += h2f_hi(p.y);
    }
    __shared__ float red[16][16][4];
    #pragma unroll
    for (int i = 0; i < 4; i++) red[t >> 4][cq][i] = acc[i];
    __syncthreads();
    if (t < 64) {
        const int c2 = t >> 2, j = t & 3;
        float s = 0.f;
        #pragma unroll
        for (int r = 0; r < 16; r++) s += red[r][c2][j];
        atomicAdd(&poolZ[g * 64 + c2 * 4 + j], s);
    }
}

// ---------------------------------------------------------------------------
// Final pooled transform across all layers:
// pooled[g][l*64+c] = sc5[l][c]*poolZ[l][g][c] + cnt[g]*sc5[l][64+c]
// ---------------------------------------------------------------------------
__global__ __launch_bounds__(256) void final_pool(
    const float* __restrict__ sc5, const float* __restrict__ poolZ,
    const int* __restrict__ cnt, float* __restrict__ pooled)
{
    const int idx = blockIdx.x * 256 + threadIdx.x; // 40960
    const int c = idx & 63;
    const int g = (idx >> 6) & 127;
    const int l = idx >> 13;
    pooled[g * PDim + l * 64 + c] =
        sc5[l * 128 + c] * poolZ[(size_t)l * Gg * 64 + g * 64 + c]
        + (float)cnt[g] * sc5[l * 128 + 64 + c];
}

// ---------------------------------------------------------------------------
// Proj head GEMM: (128,320)@(320,320)+b (f32, small).
// ---------------------------------------------------------------------------
template<bool RELU>
__global__ __launch_bounds__(256) void proj(
    const float* __restrict__ X, const float* __restrict__ W,
    const float* __restrict__ bias, float* __restrict__ Y)
{
    const int idx = blockIdx.x * 256 + threadIdx.x; // 40960 exact
    const int r = idx / PDim;
    const int c = idx - r * PDim;
    float acc = bias[c];
    #pragma unroll 8
    for (int k = 0; k < PDim; k++)
        acc = fmaf(X[r * PDim + k], W[k * PDim + c], acc);
    if constexpr (RELU) acc = fmaxf(acc, 0.f);
    Y[idx] = acc;
}

// ---------------------------------------------------------------------------
// Row-wise l2 normalize.
// ---------------------------------------------------------------------------
__global__ __launch_bounds__(64) void l2norm_rows(
    const float* __restrict__ X, float* __restrict__ out)
{
    const int r = blockIdx.x;
    const int l = threadIdx.x;
    float v[5];
    float s = 0.f;
    #pragma unroll
    for (int i = 0; i < 5; i++) {
        v[i] = X[r * PDim + i * 64 + l];
        s += v[i] * v[i];
    }
    #pragma unroll
    for (int off = 32; off > 0; off >>= 1) s += __shfl_down(s, off);
    s = __shfl(s, 0);
    const float d = fmaxf(sqrtf(s), 1e-12f);
    #pragma unroll
    for (int i = 0; i < 5; i++)
        out[r * PDim + i * 64 + l] = v[i] / d;
}

// ---------------------------------------------------------------------------
extern "C" void kernel_launch(void* const* d_in, const int* in_sizes, int n_in,
                              void* d_out, int out_size, void* d_ws, size_t ws_size,
                              hipStream_t stream)
{
    const float* x     = (const float*)d_in[0];
    const int*   ei    = (const int*)d_in[1];
    const int*   batch = (const int*)d_in[2];
    const float* Ws    = (const float*)d_in[3];
    const float* bs    = (const float*)d_in[4];
    const float* W1    = (const float*)d_in[5];
    const float* b1    = (const float*)d_in[6];
    const float* W2    = (const float*)d_in[7];
    const float* b2    = (const float*)d_in[8];
    const float* gamma = (const float*)d_in[9];
    const float* beta  = (const float*)d_in[10];
    const float* Wp1   = (const float*)d_in[11];
    const float* bp1   = (const float*)d_in[12];
    const float* Wp2   = (const float*)d_in[13];
    const float* bp2   = (const float*)d_in[14];
    float* out = (float*)d_out;

    // workspace
    ushort* Us = (ushort*)d_ws;                   // u  fp16 (N*64)  12.8MB
    ushort* Zs = Us + (size_t)Nn * 64;            // z  fp16         12.8MB
    ushort* WThi = Zs + (size_t)Nn * 64;          // 11*4096 fp16
    ushort* WTlo = WThi + 11 * 4096;
    float* pooled = (float*)(WTlo + 11 * 4096);   // (G,320)
    float* ytmp   = pooled + (size_t)Gg * PDim;
    float* ypro   = ytmp + (size_t)Gg * PDim;
    float* stats  = ypro + (size_t)Gg * PDim;     // 128
    float* sc     = stats + 128;                  // 128
    float* sc5    = sc + 128;                     // 5*128
    float* poolZ  = sc5 + 5 * 128;                // 5*G*64
    float* spart  = poolZ + 5 * Gg * 64;          // GG*128 (800KB)
    int* cnt    = (int*)(spart + (size_t)GG * 128); // 128
    int* rowptr = cnt + 128;                      // Nn+1
    int* colidx = rowptr + Nn + 1;                // Ee
    int* gCursor = colidx + Ee;                   // 128 (NB used)
    int* bucketBase = gCursor + 128;              // 128
    size_t woff = (size_t)((bucketBase + 128) - (int*)d_ws);
    woff = (woff + 1) & ~(size_t)1;
    uint2* binned = (uint2*)((int*)d_ws + woff);  // NB*BCAP*8B = 12.6MB

    hipMemsetAsync(stats, 0, 128 * sizeof(float), stream);
    hipMemsetAsync(poolZ, 0, 5 * Gg * 64 * sizeof(float), stream);

    init_csr<<<1, 128, 0, stream>>>(batch, gCursor, cnt, sc);
    conv_weights<<<11, 256, 0, stream>>>(Ws, W1, W2, WThi, WTlo);

    // bucketed CSR build
    bin_edges<<<NBLK_A, 256, 0, stream>>>(ei, gCursor, binned);
    scan_buckets<<<1, 128, 0, stream>>>(gCursor, bucketBase);
    build_csr<<<NB, 256, 0, stream>>>(binned, gCursor, bucketBase, rowptr, colidx);

    // encoder: Zs = fp16(x @ Ws + bs)   (raw z_0; BN identity in sc)
    gemm_enc<<<GG, 256, 0, stream>>>(x, WThi, WTlo, bs, Zs);

    for (int l = 0; l < Ll; l++) {
        // u = BN_{l-1} applied to inclusive sum of raw z (affine distributes)
        gather_bn<<<Nn / 32, 256, 0, stream>>>(rowptr, colidx, Zs, sc, Us);
        fused_mlp<<<GG, 256, 0, stream>>>(
            Us,
            WThi + (size_t)(1 + l) * 4096, WTlo + (size_t)(1 + l) * 4096,
            b1 + (size_t)l * 64,
            WThi + (size_t)(6 + l) * 4096, WTlo + (size_t)(6 + l) * 4096,
            b2 + (size_t)l * 64,
            Zs, spart);
        reduce_stats<<<16, 256, 0, stream>>>(spart, stats);
        bn_finalize<<<1, 64, 0, stream>>>(stats, gamma, beta, sc, sc5, l);
        pool_z<<<Gg * 8, 256, 0, stream>>>(Zs, batch, poolZ + (size_t)l * Gg * 64);
    }

    final_pool<<<160, 256, 0, stream>>>(sc5, poolZ, cnt, pooled);

    // proj head (f32)
    proj<true><<<160, 256, 0, stream>>>(pooled, Wp1, bp1, ytmp);
    proj<false><<<160, 256, 0, stream>>>(ytmp, Wp2, bp2, ypro);

    l2norm_rows<<<Gg, 64, 0, stream>>>(ypro, out);               // out0
    l2norm_rows<<<Gg, 64, 0, stream>>>(pooled, out + Gg * PDim); // out1
}